// Round 1
// baseline (1158.893 us; speedup 1.0000x reference)
//
#include <hip/hip_runtime.h>
#include <math.h>

#define BATCH 16
#define CH 3
#define CKCH 6
#define HH 256
#define WW 256
#define NSTEPS 10
#define PLANE (HH*WW)

// ---------------- K0: Hinv[i][c][ky][kx] = 1/(65536 * OTF) ----------------
// OTF = sum_{a,b in [0,5)} kerH[a][b] * cos(2*pi*(ky*(a-2)+kx*(b-2))/256)
// kerH = delta_center + sum_o rho[i,2c+o] * autocorr(K[i,2c+o])
__global__ __launch_bounds__(256) void hinv_kernel(const float* __restrict__ kerK,
                                                   const float* __restrict__ rho,
                                                   float* __restrict__ Hinv) {
  int bid = blockIdx.x;
  int chunk = bid & 7;          // 8 chunks of 8192 elements
  int ic = bid >> 3;            // 0..29
  int c = ic % CH, i = ic / CH;
  __shared__ float kerH[25];
  if (threadIdx.x < 25) {
    int a = threadIdx.x / 5, b = threadIdx.x % 5;
    float s = (a == 2 && b == 2) ? 1.0f : 0.0f;
    for (int o = 0; o < 2; ++o) {
      int ck = c * 2 + o;
      const float* Kk = kerK + (i * CKCH + ck) * 9;
      float rh = rho[i * CKCH + ck];
      float ac = 0.f;
      for (int ty = 0; ty < 3; ++ty)
        for (int tx = 0; tx < 3; ++tx) {
          int ya = a - 2 + ty, xb = b - 2 + tx;
          if (ya >= 0 && ya < 3 && xb >= 0 && xb < 3)
            ac += Kk[ya * 3 + xb] * Kk[ty * 3 + tx];
        }
      s += rh * ac;
    }
    kerH[threadIdx.x] = s;
  }
  __syncthreads();
  float kh[25];
#pragma unroll
  for (int q = 0; q < 25; ++q) kh[q] = kerH[q];
  float* out = Hinv + (size_t)(i * CH + c) * PLANE;
  const float w0 = 6.283185307179586f / 256.0f;
  for (int e = threadIdx.x; e < 8192; e += 256) {
    int idx = chunk * 8192 + e;
    int ky = idx >> 8, kx = idx & 255;
    float acc = 0.f;
#pragma unroll
    for (int a = 0; a < 5; ++a)
#pragma unroll
      for (int b = 0; b < 5; ++b) {
        float ang = w0 * (float)(ky * (a - 2) + kx * (b - 2));
        acc += kh[a * 5 + b] * cosf(ang);
      }
    out[idx] = 1.0f / (65536.0f * acc);
  }
}

// ---------------- K1: w1 = f + sum_o dwconv(rho*flip(K), p-mu) ; forward row FFT ----------------
__global__ __launch_bounds__(256) void w1_rowfft_kernel(
    const float* __restrict__ xin, const float* __restrict__ kerK,
    const float* __restrict__ rho, const float* __restrict__ p,
    const float* __restrict__ mu, float* __restrict__ Fr, float* __restrict__ Fi,
    int step) {
  int bid = blockIdx.x;
  int ypair = bid & 127;
  int bc = bid >> 7;                  // b*CH + c
  int c = bc % CH;
  int b = bc / CH;
  int half = threadIdx.x >> 7;        // which of the 2 rows this block handles
  int t = threadIdx.x & 127;
  int y0 = ypair * 2;
  int y = y0 + half;

  __shared__ float pm[2][4][WW];                 // (p-mu) rows y0-1..y0+2, 2 group channels
  __shared__ float re[2][2][WW], im[2][2][WW];   // [row][pingpong][x]
  __shared__ float twr[128], twi[128];

  if (threadIdx.x < 128) {
    float s, co;
    sincosf(-6.283185307179586f * (float)threadIdx.x / 256.0f, &s, &co);
    twr[threadIdx.x] = co; twi[threadIdx.x] = s;
  }

  for (int e = threadIdx.x; e < 2 * 4 * WW; e += 256) {
    int xx = e & 255;
    int r = (e >> 8) & 3;
    int o = e >> 10;
    int gy = y0 - 1 + r;
    float v = 0.f;
    if (gy >= 0 && gy < HH) {
      int gidx = ((b * CKCH + c * 2 + o) * HH + gy) * WW + xx;
      v = p[gidx] - mu[gidx];
    }
    pm[o][r][xx] = v;
  }

  // kerW[o][dy][dx] = rho * K[2-dy][2-dx]
  float kw[2][9];
#pragma unroll
  for (int o = 0; o < 2; ++o) {
    int ck = c * 2 + o;
    float rh = rho[step * CKCH + ck];
    const float* Kk = kerK + (step * CKCH + ck) * 9;
#pragma unroll
    for (int dy = 0; dy < 3; ++dy)
#pragma unroll
      for (int dx = 0; dx < 3; ++dx)
        kw[o][dy * 3 + dx] = rh * Kk[(2 - dy) * 3 + (2 - dx)];
  }
  __syncthreads();

  const float* xrow = xin + ((b * CH + c) * HH + y) * WW;
#pragma unroll
  for (int h = 0; h < 2; ++h) {
    int px = t + h * 128;
    float s = xrow[px];
#pragma unroll
    for (int o = 0; o < 2; ++o)
#pragma unroll
      for (int dy = 0; dy < 3; ++dy)
#pragma unroll
        for (int dx = 0; dx < 3; ++dx) {
          int xx = px + dx - 1;
          float v = (xx >= 0 && xx < WW) ? pm[o][half + dy][xx] : 0.f;
          s += kw[o][dy * 3 + dx] * v;
        }
    re[half][0][px] = s;
    im[half][0][px] = 0.f;
  }
  __syncthreads();

  // forward Stockham FFT, 8 stages
  int pp = 0;
#pragma unroll
  for (int s = 0; s < 8; ++s) {
    int m = 1 << s;
    int jm = t & ~(m - 1);
    float wr = twr[jm], wi = twi[jm];
    float ar = re[half][pp][t], ai = im[half][pp][t];
    float br = re[half][pp][t + 128], bi = im[half][pp][t + 128];
    int d0 = t + jm;
    float sr = ar - br, si = ai - bi;
    re[half][pp ^ 1][d0] = ar + br;       im[half][pp ^ 1][d0] = ai + bi;
    re[half][pp ^ 1][d0 + m] = wr * sr - wi * si;
    im[half][pp ^ 1][d0 + m] = wr * si + wi * sr;
    pp ^= 1;
    __syncthreads();
  }
  float* frow = Fr + ((size_t)(b * CH + c) * HH + y) * WW;
  float* firow = Fi + ((size_t)(b * CH + c) * HH + y) * WW;
  frow[t] = re[half][0][t];          frow[t + 128] = re[half][0][t + 128];
  firow[t] = im[half][0][t];         firow[t + 128] = im[half][0][t + 128];
}

// ---------------- K2: column FFT -> *Hinv -> inverse column FFT (8 columns/block) ----------------
__global__ __launch_bounds__(256) void colfft_kernel(float* __restrict__ Fr, float* __restrict__ Fi,
                                                     const float* __restrict__ Hinv, int step) {
  int bid = blockIdx.x;
  int xc = bid & 31;              // 32 chunks of 8 columns
  int bc = bid >> 5;              // b*CH + c
  int c = bc % CH;
  int x0 = xc * 8;
  float* fr = Fr + (size_t)bc * PLANE;
  float* fi = Fi + (size_t)bc * PLANE;
  const float* T = Hinv + (size_t)(step * CH + c) * PLANE;

  __shared__ float ar[2][HH][8], ai[2][HH][8];
  __shared__ float twr[128], twi[128];
  if (threadIdx.x < 128) {
    float s, co;
    sincosf(-6.283185307179586f * (float)threadIdx.x / 256.0f, &s, &co);
    twr[threadIdx.x] = co; twi[threadIdx.x] = s;
  }
  for (int e = threadIdx.x; e < HH * 8; e += 256) {
    int row = e >> 3, col = e & 7;
    ar[0][row][col] = fr[row * WW + x0 + col];
    ai[0][row][col] = fi[row * WW + x0 + col];
  }
  __syncthreads();

  int col = threadIdx.x & 7;
  int tb = threadIdx.x >> 3;      // 0..31
  int pp = 0;
  // forward
#pragma unroll
  for (int s = 0; s < 8; ++s) {
    int m = 1 << s;
#pragma unroll
    for (int q = 0; q < 4; ++q) {
      int tt = tb + q * 32;
      int jm = tt & ~(m - 1);
      float wr = twr[jm], wi = twi[jm];
      float a0r = ar[pp][tt][col], a0i = ai[pp][tt][col];
      float b0r = ar[pp][tt + 128][col], b0i = ai[pp][tt + 128][col];
      int d0 = tt + jm;
      float sr = a0r - b0r, si = a0i - b0i;
      ar[pp ^ 1][d0][col] = a0r + b0r;       ai[pp ^ 1][d0][col] = a0i + b0i;
      ar[pp ^ 1][d0 + m][col] = wr * sr - wi * si;
      ai[pp ^ 1][d0 + m][col] = wr * si + wi * sr;
    }
    pp ^= 1;
    __syncthreads();
  }
  // multiply by Hinv (spectrum is in buffer 0)
  for (int e = threadIdx.x; e < HH * 8; e += 256) {
    int row = e >> 3, cx = e & 7;
    float tv = T[row * WW + x0 + cx];
    ar[0][row][cx] *= tv;
    ai[0][row][cx] *= tv;
  }
  __syncthreads();
  // inverse
  pp = 0;
#pragma unroll
  for (int s = 0; s < 8; ++s) {
    int m = 1 << s;
#pragma unroll
    for (int q = 0; q < 4; ++q) {
      int tt = tb + q * 32;
      int jm = tt & ~(m - 1);
      float wr = twr[jm], wi = -twi[jm];
      float a0r = ar[pp][tt][col], a0i = ai[pp][tt][col];
      float b0r = ar[pp][tt + 128][col], b0i = ai[pp][tt + 128][col];
      int d0 = tt + jm;
      float sr = a0r - b0r, si = a0i - b0i;
      ar[pp ^ 1][d0][col] = a0r + b0r;       ai[pp ^ 1][d0][col] = a0i + b0i;
      ar[pp ^ 1][d0 + m][col] = wr * sr - wi * si;
      ai[pp ^ 1][d0 + m][col] = wr * si + wi * sr;
    }
    pp ^= 1;
    __syncthreads();
  }
  for (int e = threadIdx.x; e < HH * 8; e += 256) {
    int row = e >> 3, cx = e & 7;
    fr[row * WW + x0 + cx] = ar[0][row][cx];
    fi[row * WW + x0 + cx] = ai[0][row][cx];
  }
}

// ---------------- K3: inverse row FFT -> u (real part) ----------------
__global__ __launch_bounds__(256) void rowifft_kernel(const float* __restrict__ Fr,
                                                      const float* __restrict__ Fi,
                                                      float* __restrict__ u) {
  int bid = blockIdx.x;
  int ypair = bid & 127;
  int bc = bid >> 7;
  int half = threadIdx.x >> 7;
  int t = threadIdx.x & 127;
  int y = ypair * 2 + half;
  __shared__ float re[2][2][WW], im[2][2][WW];
  __shared__ float twr[128], twi[128];
  if (threadIdx.x < 128) {
    float s, co;
    sincosf(-6.283185307179586f * (float)threadIdx.x / 256.0f, &s, &co);
    twr[threadIdx.x] = co; twi[threadIdx.x] = s;
  }
  const float* frow = Fr + ((size_t)bc * HH + y) * WW;
  const float* firow = Fi + ((size_t)bc * HH + y) * WW;
  re[half][0][t] = frow[t];          re[half][0][t + 128] = frow[t + 128];
  im[half][0][t] = firow[t];         im[half][0][t + 128] = firow[t + 128];
  __syncthreads();
  int pp = 0;
#pragma unroll
  for (int s = 0; s < 8; ++s) {
    int m = 1 << s;
    int jm = t & ~(m - 1);
    float wr = twr[jm], wi = -twi[jm];
    float ar = re[half][pp][t], ai = im[half][pp][t];
    float br = re[half][pp][t + 128], bi = im[half][pp][t + 128];
    int d0 = t + jm;
    float sr = ar - br, si = ai - bi;
    re[half][pp ^ 1][d0] = ar + br;       im[half][pp ^ 1][d0] = ai + bi;
    re[half][pp ^ 1][d0 + m] = wr * sr - wi * si;
    im[half][pp ^ 1][d0 + m] = wr * si + wi * sr;
    pp ^= 1;
    __syncthreads();
  }
  float* urow = u + ((size_t)bc * HH + y) * WW;
  urow[t] = re[half][0][t];
  urow[t + 128] = re[half][0][t + 128];
}

// ---------------- K4: c = dwconv(K, repeat(u)); p = shrink(c+mu); mu += c - p ----------------
__global__ __launch_bounds__(256) void pmu_kernel(const float* __restrict__ u,
                                                  const float* __restrict__ kerK,
                                                  const float* __restrict__ beta,
                                                  const float* __restrict__ rho,
                                                  float* __restrict__ p, float* __restrict__ mu,
                                                  int step) {
  int bid = blockIdx.x;           // (b*CKCH + ck)*HH + y
  int y = bid & 255;
  int bck = bid >> 8;
  int ck = bck % CKCH;
  int b = bck / CKCH;
  int uc = ck >> 1;
  __shared__ float ur[3][WW + 2];
  for (int e = threadIdx.x; e < 3 * (WW + 2); e += 256) {
    int r = e / (WW + 2), xx = e % (WW + 2);
    int gy = y - 1 + r, gx = xx - 1;
    float v = 0.f;
    if (gy >= 0 && gy < HH && gx >= 0 && gx < WW)
      v = u[((b * CH + uc) * HH + gy) * WW + gx];
    ur[r][xx] = v;
  }
  float k9[9];
  const float* Kk = kerK + (step * CKCH + ck) * 9;
#pragma unroll
  for (int q = 0; q < 9; ++q) k9[q] = Kk[q];
  float gm = beta[step * CKCH + ck] / rho[step * CKCH + ck];
  __syncthreads();
  int x = threadIdx.x;
  float cval = 0.f;
#pragma unroll
  for (int dy = 0; dy < 3; ++dy)
#pragma unroll
    for (int dx = 0; dx < 3; ++dx)
      cval += k9[dy * 3 + dx] * ur[dy][x + dx];
  int gidx = ((b * CKCH + ck) * HH + y) * WW + x;
  float m0 = mu[gidx];
  float v = cval + m0;
  float av = fabsf(v) - gm;
  float pn = (av > 0.f) ? ((v > 0.f) ? av : -av) : 0.f;
  p[gidx] = pn;
  mu[gidx] = m0 + cval - pn;
}

extern "C" void kernel_launch(void* const* d_in, const int* in_sizes, int n_in,
                              void* d_out, int out_size, void* d_ws, size_t ws_size,
                              hipStream_t stream) {
  const float* x = (const float*)d_in[0];
  const float* kerK = (const float*)d_in[1];
  const float* beta = (const float*)d_in[2];
  const float* rho = (const float*)d_in[3];
  float* out = (float*)d_out;
  float* ws = (float*)d_ws;

  const size_t PMU = (size_t)BATCH * CKCH * PLANE;  // 6291456
  const size_t UPL = (size_t)BATCH * CH * PLANE;    // 3145728
  float* p = ws;
  float* mu = p + PMU;
  float* Fr = mu + PMU;
  float* Fi = Fr + UPL;
  float* Hinv = Fi + UPL;

  hipMemsetAsync(p, 0, 2 * PMU * sizeof(float), stream);
  hinv_kernel<<<NSTEPS * CH * 8, 256, 0, stream>>>(kerK, rho, Hinv);

  for (int i = 0; i < NSTEPS; ++i) {
    w1_rowfft_kernel<<<BATCH * CH * 128, 256, 0, stream>>>(x, kerK, rho, p, mu, Fr, Fi, i);
    colfft_kernel<<<BATCH * CH * 32, 256, 0, stream>>>(Fr, Fi, Hinv, i);
    rowifft_kernel<<<BATCH * CH * 128, 256, 0, stream>>>(Fr, Fi, out);
    if (i < NSTEPS - 1)
      pmu_kernel<<<BATCH * CKCH * HH, 256, 0, stream>>>(out, kerK, beta, rho, p, mu, i);
  }
}

// Round 2
// 807.313 us; speedup vs baseline: 1.4355x; 1.4355x over previous
//
#include <hip/hip_runtime.h>
#include <math.h>

#define BATCH 16
#define CH 3
#define CKCH 6
#define HH 256
#define WW 256
#define NSTEPS 10
#define PLANE (HH*WW)
#define SW 132                 // half-spectrum row stride (129 used)
#define SPLANE (HH*SW)

// ---------------- Hinv[i][c][ky][kx<=128] = 1/(65536*OTF) via cos table ----------------
__global__ __launch_bounds__(256) void hinv2_kernel(const float* __restrict__ kerK,
                                                    const float* __restrict__ rho,
                                                    float* __restrict__ Hinv) {
  int bid = blockIdx.x;
  int ypair = bid & 127;
  int ic = bid >> 7;            // 0..29
  int c = ic % CH, i = ic / CH;
  __shared__ float kerH[25];
  __shared__ float ctab[256];
  int tid = threadIdx.x;
  if (tid < 25) {
    int a = tid / 5, b = tid % 5;
    float s = (a == 2 && b == 2) ? 1.0f : 0.0f;
    for (int o = 0; o < 2; ++o) {
      int ck = c * 2 + o;
      const float* Kk = kerK + (i * CKCH + ck) * 9;
      float rh = rho[i * CKCH + ck];
      float ac = 0.f;
      for (int ty = 0; ty < 3; ++ty)
        for (int tx = 0; tx < 3; ++tx) {
          int ya = a - 2 + ty, xb = b - 2 + tx;
          if (ya >= 0 && ya < 3 && xb >= 0 && xb < 3)
            ac += Kk[ya * 3 + xb] * Kk[ty * 3 + tx];
        }
      s += rh * ac;
    }
    kerH[tid] = s;
  }
  ctab[tid] = cosf(6.283185307179586f * (float)tid / 256.0f);
  __syncthreads();
  float kh[25];
#pragma unroll
  for (int q = 0; q < 25; ++q) kh[q] = kerH[q];
  int half = tid >> 7, t = tid & 127;
  int ky = ypair * 2 + half;
  float* out = Hinv + (size_t)ic * SPLANE + ky * SW;
#pragma unroll
  for (int rep = 0; rep < 2; ++rep) {
    if (rep == 1 && t != 0) break;
    int kx = (rep == 0) ? t : 128;
    float acc = 0.f;
#pragma unroll
    for (int a = 0; a < 5; ++a)
#pragma unroll
      for (int b = 0; b < 5; ++b)
        acc += kh[a * 5 + b] * ctab[(ky * (a - 2) + kx * (b - 2)) & 255];
    out[kx] = 1.0f / (65536.0f * acc);
  }
}

// ------- fused: pmu(step-1) + w1(step) + packed real row-FFT -> half spectra -------
// strip of 8 output rows per block; p never hits global; mu ping-pong.
__global__ __launch_bounds__(256) void step_kernel(
    const float* __restrict__ xin, const float* __restrict__ kerK,
    const float* __restrict__ beta, const float* __restrict__ rho,
    const float* __restrict__ uin, const float* __restrict__ muIn,
    float* __restrict__ muOut, float* __restrict__ Fr, float* __restrict__ Fi,
    int wstep) {
  int bid = blockIdx.x;
  int strip = bid & 31;
  int bc = bid >> 5;
  int c = bc % CH, b = bc / CH;
  int y0 = strip * 8;
  int tid = threadIdx.x;
  bool first = (wstep == 0);

  __shared__ float su[12][WW];           // u rows y0-2 .. y0+9
  __shared__ float sd[2][10][WW];        // (p-mu) rows y0-1 .. y0+8, 2 group ch
  __shared__ float fR[2][2][WW], fI[2][2][WW];
  __shared__ float twr[128], twi[128];

  if (tid < 128) {
    float s, co;
    sincosf(-6.283185307179586f * (float)tid / 256.0f, &s, &co);
    twr[tid] = co; twi[tid] = s;
  }

  if (!first) {
    for (int e = tid; e < 12 * WW; e += 256) {
      int j = e >> 8, xx = e & 255;
      int gy = y0 - 2 + j;
      su[j][xx] = (gy >= 0 && gy < HH) ? uin[((b * CH + c) * HH + gy) * WW + xx] : 0.f;
    }
  }
  __syncthreads();

  if (!first) {
    int ps = wstep - 1;
    int x = tid;
#pragma unroll
    for (int o = 0; o < 2; ++o) {
      int ck = c * 2 + o;
      const float* Kp = kerK + (ps * CKCH + ck) * 9;
      float k9[9];
#pragma unroll
      for (int q = 0; q < 9; ++q) k9[q] = Kp[q];
      float gm = beta[ps * CKCH + ck] / rho[ps * CKCH + ck];
      for (int rr = 0; rr < 10; ++rr) {
        int y = y0 - 1 + rr;
        float dval = 0.f;
        if (y >= 0 && y < HH) {
          float cval = 0.f;
#pragma unroll
          for (int dy = 0; dy < 3; ++dy)
#pragma unroll
            for (int dx = 0; dx < 3; ++dx) {
              int xx = x + dx - 1;
              float v = (xx >= 0 && xx < WW) ? su[rr + dy][xx] : 0.f;
              cval += k9[dy * 3 + dx] * v;
            }
          int gidx = ((b * CKCH + ck) * HH + y) * WW + x;
          float m0 = muIn[gidx];
          float vv = cval + m0;
          float av = fabsf(vv) - gm;
          float pn = (av > 0.f) ? ((vv > 0.f) ? av : -av) : 0.f;
          float mn = m0 + cval - pn;
          dval = pn - mn;
          if (rr >= 1 && rr <= 8) muOut[gidx] = mn;
        }
        sd[o][rr][x] = dval;
      }
    }
  }
  __syncthreads();

  float kw[2][9];
#pragma unroll
  for (int o = 0; o < 2; ++o) {
    int ck = c * 2 + o;
    float rh = rho[wstep * CKCH + ck];
    const float* Kk = kerK + (wstep * CKCH + ck) * 9;
#pragma unroll
    for (int dy = 0; dy < 3; ++dy)
#pragma unroll
      for (int dx = 0; dx < 3; ++dx)
        kw[o][dy * 3 + dx] = rh * Kk[(2 - dy) * 3 + (2 - dx)];
  }

  int unit = tid >> 7, t = tid & 127;
  for (int pass = 0; pass < 2; ++pass) {
    int q = pass * 2 + unit;
    int sa = 2 * q, sb = sa + 1;
    int ya = y0 + sa, yb = y0 + sb;
    const float* xra = xin + ((b * CH + c) * HH + ya) * WW;
    const float* xrb = xin + ((b * CH + c) * HH + yb) * WW;
#pragma unroll
    for (int h = 0; h < 2; ++h) {
      int px = t + h * 128;
      float va = xra[px], vb = xrb[px];
      if (!first) {
#pragma unroll
        for (int o = 0; o < 2; ++o)
#pragma unroll
          for (int dy = 0; dy < 3; ++dy)
#pragma unroll
            for (int dx = 0; dx < 3; ++dx) {
              int xx = px + dx - 1;
              if (xx >= 0 && xx < WW) {
                float w = kw[o][dy * 3 + dx];
                va += w * sd[o][sa + dy][xx];
                vb += w * sd[o][sb + dy][xx];
              }
            }
      }
      fR[unit][0][px] = va;
      fI[unit][0][px] = vb;
    }
    __syncthreads();
    int pp = 0;
#pragma unroll
    for (int s = 0; s < 8; ++s) {
      int m = 1 << s;
      int jm = t & ~(m - 1);
      float wr = twr[jm], wi = twi[jm];
      float ar = fR[unit][pp][t], ai = fI[unit][pp][t];
      float br = fR[unit][pp][t + 128], bi = fI[unit][pp][t + 128];
      int d0 = t + jm;
      float sr = ar - br, si = ai - bi;
      fR[unit][pp ^ 1][d0] = ar + br;       fI[unit][pp ^ 1][d0] = ai + bi;
      fR[unit][pp ^ 1][d0 + m] = wr * sr - wi * si;
      fI[unit][pp ^ 1][d0 + m] = wr * si + wi * sr;
      pp ^= 1;
      __syncthreads();
    }
    {
      int k = t, mI = (256 - t) & 255;
      float Rk = fR[unit][0][k], Ik = fI[unit][0][k];
      float Rm = fR[unit][0][mI], Im = fI[unit][0][mI];
      size_t ra = ((size_t)bc * HH + ya) * SW;
      size_t rb = ((size_t)bc * HH + yb) * SW;
      Fr[ra + k] = 0.5f * (Rk + Rm);   Fi[ra + k] = 0.5f * (Ik - Im);
      Fr[rb + k] = 0.5f * (Ik + Im);   Fi[rb + k] = 0.5f * (Rm - Rk);
      if (t == 0) {
        Fr[ra + 128] = fR[unit][0][128]; Fi[ra + 128] = 0.f;
        Fr[rb + 128] = fI[unit][0][128]; Fi[rb + 128] = 0.f;
      }
    }
    __syncthreads();
  }
}

// ---------------- column FFT -> *Hinv -> inverse column FFT (129 cols) ----------------
__global__ __launch_bounds__(256) void colfft_kernel(float* __restrict__ Fr, float* __restrict__ Fi,
                                                     const float* __restrict__ Hinv, int step) {
  int bid = blockIdx.x;
  int g = bid % 17;
  int bc = bid / 17;
  int c = bc % CH;
  int x0 = g * 8;
  float* fr = Fr + (size_t)bc * SPLANE;
  float* fi = Fi + (size_t)bc * SPLANE;
  const float* T = Hinv + (size_t)(step * CH + c) * SPLANE;

  __shared__ float ar[2][HH][8], ai[2][HH][8];
  __shared__ float twr[128], twi[128];
  if (threadIdx.x < 128) {
    float s, co;
    sincosf(-6.283185307179586f * (float)threadIdx.x / 256.0f, &s, &co);
    twr[threadIdx.x] = co; twi[threadIdx.x] = s;
  }
  for (int e = threadIdx.x; e < HH * 8; e += 256) {
    int row = e >> 3, col = e & 7;
    int kx = x0 + col;
    bool act = (kx <= 128);
    ar[0][row][col] = act ? fr[row * SW + kx] : 0.f;
    ai[0][row][col] = act ? fi[row * SW + kx] : 0.f;
  }
  __syncthreads();

  int col = threadIdx.x & 7;
  int tb = threadIdx.x >> 3;
  int pp = 0;
#pragma unroll
  for (int s = 0; s < 8; ++s) {
    int m = 1 << s;
#pragma unroll
    for (int q = 0; q < 4; ++q) {
      int tt = tb + q * 32;
      int jm = tt & ~(m - 1);
      float wr = twr[jm], wi = twi[jm];
      float a0r = ar[pp][tt][col], a0i = ai[pp][tt][col];
      float b0r = ar[pp][tt + 128][col], b0i = ai[pp][tt + 128][col];
      int d0 = tt + jm;
      float sr = a0r - b0r, si = a0i - b0i;
      ar[pp ^ 1][d0][col] = a0r + b0r;       ai[pp ^ 1][d0][col] = a0i + b0i;
      ar[pp ^ 1][d0 + m][col] = wr * sr - wi * si;
      ai[pp ^ 1][d0 + m][col] = wr * si + wi * sr;
    }
    pp ^= 1;
    __syncthreads();
  }
  for (int e = threadIdx.x; e < HH * 8; e += 256) {
    int row = e >> 3, cx = e & 7;
    int kx = x0 + cx;
    if (kx <= 128) {
      float tv = T[row * SW + kx];
      ar[0][row][cx] *= tv;
      ai[0][row][cx] *= tv;
    }
  }
  __syncthreads();
  pp = 0;
#pragma unroll
  for (int s = 0; s < 8; ++s) {
    int m = 1 << s;
#pragma unroll
    for (int q = 0; q < 4; ++q) {
      int tt = tb + q * 32;
      int jm = tt & ~(m - 1);
      float wr = twr[jm], wi = -twi[jm];
      float a0r = ar[pp][tt][col], a0i = ai[pp][tt][col];
      float b0r = ar[pp][tt + 128][col], b0i = ai[pp][tt + 128][col];
      int d0 = tt + jm;
      float sr = a0r - b0r, si = a0i - b0i;
      ar[pp ^ 1][d0][col] = a0r + b0r;       ai[pp ^ 1][d0][col] = a0i + b0i;
      ar[pp ^ 1][d0 + m][col] = wr * sr - wi * si;
      ai[pp ^ 1][d0 + m][col] = wr * si + wi * sr;
    }
    pp ^= 1;
    __syncthreads();
  }
  for (int e = threadIdx.x; e < HH * 8; e += 256) {
    int row = e >> 3, cx = e & 7;
    int kx = x0 + cx;
    if (kx <= 128) {
      fr[row * SW + kx] = ar[0][row][cx];
      fi[row * SW + kx] = ai[0][row][cx];
    }
  }
}

// ------- packed inverse row FFT: two rows per transform from half spectra -> u -------
__global__ __launch_bounds__(256) void rowinv_kernel(const float* __restrict__ Fr,
                                                     const float* __restrict__ Fi,
                                                     float* __restrict__ uout) {
  int bid = blockIdx.x;
  int pq = bid & 63;
  int bc = bid >> 6;
  int unit = threadIdx.x >> 7, t = threadIdx.x & 127;
  int pr = pq * 2 + unit;
  int ya = 2 * pr, yb = ya + 1;
  __shared__ float sAr[2][129], sAi[2][129], sBr[2][129], sBi[2][129];
  __shared__ float fR[2][2][WW], fI[2][2][WW];
  __shared__ float twr[128], twi[128];
  if (threadIdx.x < 128) {
    float s, co;
    sincosf(-6.283185307179586f * (float)threadIdx.x / 256.0f, &s, &co);
    twr[threadIdx.x] = co; twi[threadIdx.x] = s;
  }
  size_t ra = ((size_t)bc * HH + ya) * SW;
  size_t rb = ((size_t)bc * HH + yb) * SW;
  sAr[unit][t] = Fr[ra + t];  sAi[unit][t] = Fi[ra + t];
  sBr[unit][t] = Fr[rb + t];  sBi[unit][t] = Fi[rb + t];
  if (t == 0) {
    sAr[unit][128] = Fr[ra + 128];  sAi[unit][128] = Fi[ra + 128];
    sBr[unit][128] = Fr[rb + 128];  sBi[unit][128] = Fi[rb + 128];
  }
  __syncthreads();
  {
    float zr0 = sAr[unit][t] - sBi[unit][t];
    float zi0 = sAi[unit][t] + sBr[unit][t];
    fR[unit][0][t] = zr0;  fI[unit][0][t] = zi0;
    float zr1, zi1;
    if (t == 0) {
      zr1 = sAr[unit][128] - sBi[unit][128];
      zi1 = sAi[unit][128] + sBr[unit][128];
    } else {
      int m = 128 - t;
      zr1 = sAr[unit][m] + sBi[unit][m];
      zi1 = sBr[unit][m] - sAi[unit][m];
    }
    fR[unit][0][t + 128] = zr1;  fI[unit][0][t + 128] = zi1;
  }
  __syncthreads();
  int pp = 0;
#pragma unroll
  for (int s = 0; s < 8; ++s) {
    int m = 1 << s;
    int jm = t & ~(m - 1);
    float wr = twr[jm], wi = -twi[jm];
    float ar = fR[unit][pp][t], ai = fI[unit][pp][t];
    float br = fR[unit][pp][t + 128], bi = fI[unit][pp][t + 128];
    int d0 = t + jm;
    float sr = ar - br, si = ai - bi;
    fR[unit][pp ^ 1][d0] = ar + br;       fI[unit][pp ^ 1][d0] = ai + bi;
    fR[unit][pp ^ 1][d0 + m] = wr * sr - wi * si;
    fI[unit][pp ^ 1][d0 + m] = wr * si + wi * sr;
    pp ^= 1;
    __syncthreads();
  }
  float* ua = uout + ((size_t)bc * HH + ya) * WW;
  float* ub = uout + ((size_t)bc * HH + yb) * WW;
  ua[t] = fR[unit][0][t];        ua[t + 128] = fR[unit][0][t + 128];
  ub[t] = fI[unit][0][t];        ub[t + 128] = fI[unit][0][t + 128];
}

extern "C" void kernel_launch(void* const* d_in, const int* in_sizes, int n_in,
                              void* d_out, int out_size, void* d_ws, size_t ws_size,
                              hipStream_t stream) {
  const float* x = (const float*)d_in[0];
  const float* kerK = (const float*)d_in[1];
  const float* beta = (const float*)d_in[2];
  const float* rho = (const float*)d_in[3];
  float* out = (float*)d_out;
  float* ws = (float*)d_ws;

  const size_t PMU = (size_t)BATCH * CKCH * PLANE;   // 6291456
  const size_t UPL = (size_t)BATCH * CH * PLANE;     // 3145728
  const size_t SPL = (size_t)BATCH * CH * SPLANE;    // 1622016
  float* muA = ws;
  float* muB = muA + PMU;
  float* u = muB + PMU;
  float* Fr = u + UPL;
  float* Fi = Fr + SPL;
  float* Hinv = Fi + SPL;

  hipMemsetAsync(muA, 0, PMU * sizeof(float), stream);
  hinv2_kernel<<<30 * 128, 256, 0, stream>>>(kerK, rho, Hinv);

  for (int i = 0; i < NSTEPS; ++i) {
    float* dst = (i == NSTEPS - 1) ? out : u;
    const float* mi = (i & 1) ? muA : muB;
    float* mo = (i & 1) ? muB : muA;
    step_kernel<<<BATCH * CH * 32, 256, 0, stream>>>(x, kerK, beta, rho, u, mi, mo, Fr, Fi, i);
    colfft_kernel<<<BATCH * CH * 17, 256, 0, stream>>>(Fr, Fi, Hinv, i);
    rowinv_kernel<<<BATCH * CH * 64, 256, 0, stream>>>(Fr, Fi, dst);
  }
}

// Round 3
// 544.297 us; speedup vs baseline: 2.1292x; 1.4832x over previous
//
#include <hip/hip_runtime.h>
#include <math.h>

#define BATCH 16
#define CH 3
#define CKCH 6
#define HH 256
#define WW 256
#define NSTEPS 10
#define SW 132                  // half-spectrum row stride (129 used), in float2 units
#define HSP (HH*SW)

// ---------------- Hinv[i][c][ky][kx<=128] = 1/(65536*OTF) via cos table ----------------
__global__ __launch_bounds__(256) void hinv2_kernel(const float* __restrict__ kerK,
                                                    const float* __restrict__ rho,
                                                    float* __restrict__ Hinv) {
  int bid = blockIdx.x;
  int ypair = bid & 127;
  int ic = bid >> 7;            // 0..29
  int c = ic % CH, i = ic / CH;
  __shared__ float kerH[25];
  __shared__ float ctab[256];
  int tid = threadIdx.x;
  if (tid < 25) {
    int a = tid / 5, b = tid % 5;
    float s = (a == 2 && b == 2) ? 1.0f : 0.0f;
    for (int o = 0; o < 2; ++o) {
      int ck = c * 2 + o;
      const float* Kk = kerK + (i * CKCH + ck) * 9;
      float rh = rho[i * CKCH + ck];
      float ac = 0.f;
      for (int ty = 0; ty < 3; ++ty)
        for (int tx = 0; tx < 3; ++tx) {
          int ya = a - 2 + ty, xb = b - 2 + tx;
          if (ya >= 0 && ya < 3 && xb >= 0 && xb < 3)
            ac += Kk[ya * 3 + xb] * Kk[ty * 3 + tx];
        }
      s += rh * ac;
    }
    kerH[tid] = s;
  }
  ctab[tid] = cosf(6.283185307179586f * (float)tid / 256.0f);
  __syncthreads();
  float kh[25];
#pragma unroll
  for (int q = 0; q < 25; ++q) kh[q] = kerH[q];
  int half = tid >> 7, t = tid & 127;
  int ky = ypair * 2 + half;
  float* out = Hinv + (size_t)ic * HSP + ky * SW;
#pragma unroll
  for (int rep = 0; rep < 2; ++rep) {
    if (rep == 1 && t != 0) break;
    int kx = (rep == 0) ? t : 128;
    float acc = 0.f;
#pragma unroll
    for (int a = 0; a < 5; ++a)
#pragma unroll
      for (int b = 0; b < 5; ++b)
        acc += kh[a * 5 + b] * ctab[(ky * (a - 2) + kx * (b - 2)) & 255];
    out[kx] = 1.0f / (65536.0f * acc);
  }
}

// ------- bigstep: inv-rowFFT(prev spectra) + pmu(step-1) + w1(step) + fwd rowFFT -------
// wstep==0: w1=x only. wstep in 1..9: full. wstep==10: final inverse -> uout.
__global__ __launch_bounds__(256, 3) void bigstep_kernel(
    const float* __restrict__ xin, const float* __restrict__ kerK,
    const float* __restrict__ beta, const float* __restrict__ rho,
    const float2* __restrict__ specIn, const float* __restrict__ muIn,
    float* __restrict__ muOut, float2* __restrict__ specOut,
    float* __restrict__ uout, int wstep) {
  int bid = blockIdx.x;
  int strip = bid & 31;
  int bc = bid >> 5;
  int c = bc % CH, b = bc / CH;
  int y0 = strip * 8;
  int tid = threadIdx.x;
  int u = tid >> 6, l = tid & 63;
  bool final_ = (wstep == 10);
  bool first = (wstep == 0);

  __shared__ float su[12][264];          // u rows y0-2..y0+9, data at [4..259]
  __shared__ float sd[2][10][264];       // d = p-mu rows y0-1..y0+8
  __shared__ float2 zz[4][2][256];       // per-wave FFT ping-pong (complex)
  __shared__ float2 tw[128];

  if (tid < 128) {
    float sn, cs;
    sincosf(-6.283185307179586f * (float)tid / 256.0f, &sn, &cs);
    tw[tid] = make_float2(cs, sn);
  }
  __syncthreads();

  // ---- phase 1: packed inverse row FFTs (wave-local) ----
  if (wstep >= 1) {
    int nround = final_ ? 1 : 2;
    for (int round = 0; round < nround; ++round) {
      int j = final_ ? (u + 1) : (round * 4 + u);
      bool act = (j < 6);
      int ya = y0 - 2 + 2 * j;
      if (act && ya >= 0 && ya < HH) {
        const float2* Ar = specIn + ((size_t)bc * HH + ya) * SW;
        const float2* Br = Ar + SW;
#pragma unroll
        for (int h = 0; h < 2; ++h) {
          int t = l + h * 64;
          float2 A = Ar[t], B = Br[t];
          zz[u][0][t] = make_float2(A.x - B.y, A.y + B.x);
          int mI = 128 - t;
          float2 Am = Ar[mI], Bm = Br[mI];
          float2 zh;
          if (t == 0) zh = make_float2(Am.x - Bm.y, Am.y + Bm.x);
          else        zh = make_float2(Am.x + Bm.y, Bm.x - Am.y);
          zz[u][0][t + 128] = zh;
        }
        __builtin_amdgcn_wave_barrier();
        int pp = 0;
#pragma unroll
        for (int s = 0; s < 8; ++s) {
          int m = 1 << s;
#pragma unroll
          for (int h = 0; h < 2; ++h) {
            int t = l + h * 64;
            int jm = t & ~(m - 1);
            float2 w = tw[jm];
            float2 a = zz[u][pp][t], b2 = zz[u][pp][t + 128];
            float dx = a.x - b2.x, dy = a.y - b2.y;
            zz[u][pp ^ 1][t + jm] = make_float2(a.x + b2.x, a.y + b2.y);
            zz[u][pp ^ 1][t + jm + m] =
                make_float2(w.x * dx + w.y * dy, w.x * dy - w.y * dx);  // conj tw
          }
          pp ^= 1;
          __builtin_amdgcn_wave_barrier();
        }
        if (final_) {
          float* oa = uout + ((size_t)bc * HH + ya) * WW;
#pragma unroll
          for (int h = 0; h < 4; ++h) {
            int xx = l + h * 64;
            float2 z = zz[u][0][xx];
            oa[xx] = z.x;
            oa[WW + xx] = z.y;
          }
        } else {
          int r0 = 2 * j;
#pragma unroll
          for (int h = 0; h < 4; ++h) {
            int xx = l + h * 64;
            float2 z = zz[u][0][xx];
            su[r0][4 + xx] = z.x;
            su[r0 + 1][4 + xx] = z.y;
          }
        }
      } else if (act) {
        int r0 = 2 * j;
        for (int k2 = l; k2 < 264; k2 += 64) { su[r0][k2] = 0.f; su[r0 + 1][k2] = 0.f; }
      }
    }
  }
  if (final_) return;

  // ---- phase 2: c = dwconv(K[step-1], u); soft-threshold; mu update; d -> sd ----
  if (!first) {
    __syncthreads();
    bool muZero = (wstep == 1);
    int ps = wstep - 1;
#pragma unroll 1
    for (int it = 0; it < 5; ++it) {
      int task = it * 4 + u;          // 0..19 = 2 o * 10 rows
      int o = task / 10, rr = task % 10;
      int y = y0 - 1 + rr;
      int ck = c * 2 + o;
      float4 dq = make_float4(0.f, 0.f, 0.f, 0.f);
      if (y >= 0 && y < HH) {
        const float* Kp = kerK + (ps * CKCH + ck) * 9;
        float kk[9];
#pragma unroll
        for (int q = 0; q < 9; ++q) kk[q] = Kp[q];
        float gm = beta[ps * CKCH + ck] / rho[ps * CKCH + ck];
        float4 c4 = make_float4(0.f, 0.f, 0.f, 0.f);
#pragma unroll
        for (int dy = 0; dy < 3; ++dy) {
          float4 mid = *(const float4*)&su[rr + dy][4 + 4 * l];
          float lft = __shfl_up(mid.w, 1); if (l == 0) lft = 0.f;
          float rgt = __shfl_down(mid.x, 1); if (l == 63) rgt = 0.f;
          float w0 = kk[dy * 3], w1 = kk[dy * 3 + 1], w2 = kk[dy * 3 + 2];
          c4.x += w0 * lft   + w1 * mid.x + w2 * mid.y;
          c4.y += w0 * mid.x + w1 * mid.y + w2 * mid.z;
          c4.z += w0 * mid.y + w1 * mid.z + w2 * mid.w;
          c4.w += w0 * mid.z + w1 * mid.w + w2 * rgt;
        }
        size_t gidx = (((size_t)b * CKCH + ck) * HH + y) * WW + 4 * l;
        float4 m4 = make_float4(0.f, 0.f, 0.f, 0.f);
        if (!muZero) m4 = *(const float4*)(muIn + gidx);
        float4 mn4;
        {
          float v = c4.x + m4.x, av = fabsf(v) - gm;
          float pn = (av > 0.f) ? ((v > 0.f) ? av : -av) : 0.f;
          mn4.x = m4.x + c4.x - pn; dq.x = pn - mn4.x;
        }
        {
          float v = c4.y + m4.y, av = fabsf(v) - gm;
          float pn = (av > 0.f) ? ((v > 0.f) ? av : -av) : 0.f;
          mn4.y = m4.y + c4.y - pn; dq.y = pn - mn4.y;
        }
        {
          float v = c4.z + m4.z, av = fabsf(v) - gm;
          float pn = (av > 0.f) ? ((v > 0.f) ? av : -av) : 0.f;
          mn4.z = m4.z + c4.z - pn; dq.z = pn - mn4.z;
        }
        {
          float v = c4.w + m4.w, av = fabsf(v) - gm;
          float pn = (av > 0.f) ? ((v > 0.f) ? av : -av) : 0.f;
          mn4.w = m4.w + c4.w - pn; dq.w = pn - mn4.w;
        }
        if (rr >= 1 && rr <= 8) *(float4*)(muOut + gidx) = mn4;
      }
      *(float4*)&sd[o][rr][4 + 4 * l] = dq;
    }
  }
  __syncthreads();

  // ---- phase 3: w1 = f + sum_o conv(rho*flipK, d); packed forward row FFT ----
  int ya = y0 + 2 * u;
  const float4* xa = (const float4*)(xin + ((size_t)(b * CH + c) * HH + ya) * WW);
  float4 va = xa[l], vb = xa[64 + l];
  if (!first) {
#pragma unroll
    for (int o = 0; o < 2; ++o) {
      int ck = c * 2 + o;
      float rh = rho[wstep * CKCH + ck];
      const float* Kk = kerK + (wstep * CKCH + ck) * 9;
      float kw[9];
#pragma unroll
      for (int dy = 0; dy < 3; ++dy)
#pragma unroll
        for (int dx = 0; dx < 3; ++dx)
          kw[dy * 3 + dx] = rh * Kk[(2 - dy) * 3 + (2 - dx)];
      float4 mid[4]; float lf[4], rg[4];
#pragma unroll
      for (int r4 = 0; r4 < 4; ++r4) {
        mid[r4] = *(const float4*)&sd[o][2 * u + r4][4 + 4 * l];
        lf[r4] = __shfl_up(mid[r4].w, 1); if (l == 0) lf[r4] = 0.f;
        rg[r4] = __shfl_down(mid[r4].x, 1); if (l == 63) rg[r4] = 0.f;
      }
#pragma unroll
      for (int dy = 0; dy < 3; ++dy) {
        float w0 = kw[dy * 3], w1 = kw[dy * 3 + 1], w2 = kw[dy * 3 + 2];
        va.x += w0 * lf[dy]     + w1 * mid[dy].x   + w2 * mid[dy].y;
        va.y += w0 * mid[dy].x  + w1 * mid[dy].y   + w2 * mid[dy].z;
        va.z += w0 * mid[dy].y  + w1 * mid[dy].z   + w2 * mid[dy].w;
        va.w += w0 * mid[dy].z  + w1 * mid[dy].w   + w2 * rg[dy];
        vb.x += w0 * lf[dy+1]    + w1 * mid[dy+1].x + w2 * mid[dy+1].y;
        vb.y += w0 * mid[dy+1].x + w1 * mid[dy+1].y + w2 * mid[dy+1].z;
        vb.z += w0 * mid[dy+1].y + w1 * mid[dy+1].z + w2 * mid[dy+1].w;
        vb.w += w0 * mid[dy+1].z + w1 * mid[dy+1].w + w2 * rg[dy+1];
      }
    }
  }
  *(float4*)&zz[u][0][4 * l]     = make_float4(va.x, vb.x, va.y, vb.y);
  *(float4*)&zz[u][0][4 * l + 2] = make_float4(va.z, vb.z, va.w, vb.w);
  __builtin_amdgcn_wave_barrier();
  int pp = 0;
#pragma unroll
  for (int s = 0; s < 8; ++s) {
    int m = 1 << s;
#pragma unroll
    for (int h = 0; h < 2; ++h) {
      int t = l + h * 64;
      int jm = t & ~(m - 1);
      float2 w = tw[jm];
      float2 a = zz[u][pp][t], b2 = zz[u][pp][t + 128];
      float dx = a.x - b2.x, dy2 = a.y - b2.y;
      zz[u][pp ^ 1][t + jm] = make_float2(a.x + b2.x, a.y + b2.y);
      zz[u][pp ^ 1][t + jm + m] =
          make_float2(w.x * dx - w.y * dy2, w.x * dy2 + w.y * dx);
    }
    pp ^= 1;
    __builtin_amdgcn_wave_barrier();
  }
  float2* Sa = specOut + ((size_t)bc * HH + ya) * SW;
  float2* Sb = Sa + SW;
#pragma unroll
  for (int h = 0; h < 2; ++h) {
    int k = l + h * 64;
    int mI = (256 - k) & 255;
    float2 zk = zz[u][0][k], zm = zz[u][0][mI];
    Sa[k] = make_float2(0.5f * (zk.x + zm.x), 0.5f * (zk.y - zm.y));
    Sb[k] = make_float2(0.5f * (zk.y + zm.y), 0.5f * (zm.x - zk.x));
  }
  if (l == 0) {
    float2 z1 = zz[u][0][128];
    Sa[128] = make_float2(z1.x, 0.f);
    Sb[128] = make_float2(z1.y, 0.f);
  }
}

// ---------------- column FFT -> *Hinv -> inverse column FFT (float2, in-place) ----------------
__global__ __launch_bounds__(256, 4) void colfft_kernel(float2* __restrict__ spec,
                                                        const float* __restrict__ Hinv, int step) {
  int bid = blockIdx.x;
  int g = bid % 17;
  int bc = bid / 17;
  int c = bc % CH;
  int x0 = g * 8;
  float2* f = spec + (size_t)bc * HSP;
  const float* T = Hinv + (size_t)(step * CH + c) * HSP;

  __shared__ float2 az[2][HH][9];
  __shared__ float2 tw[128];
  if (threadIdx.x < 128) {
    float sn, cs;
    sincosf(-6.283185307179586f * (float)threadIdx.x / 256.0f, &sn, &cs);
    tw[threadIdx.x] = make_float2(cs, sn);
  }
  for (int e = threadIdx.x; e < HH * 8; e += 256) {
    int row = e >> 3, col = e & 7;
    int kx = x0 + col;
    az[0][row][col] = (kx <= 128) ? f[row * SW + kx] : make_float2(0.f, 0.f);
  }
  __syncthreads();

  int col = threadIdx.x & 7;
  int tb = threadIdx.x >> 3;
  int pp = 0;
#pragma unroll
  for (int s = 0; s < 8; ++s) {
    int m = 1 << s;
#pragma unroll
    for (int q = 0; q < 4; ++q) {
      int tt = tb + q * 32;
      int jm = tt & ~(m - 1);
      float2 w = tw[jm];
      float2 a = az[pp][tt][col], b2 = az[pp][tt + 128][col];
      float dx = a.x - b2.x, dy = a.y - b2.y;
      az[pp ^ 1][tt + jm][col] = make_float2(a.x + b2.x, a.y + b2.y);
      az[pp ^ 1][tt + jm + m][col] = make_float2(w.x * dx - w.y * dy, w.x * dy + w.y * dx);
    }
    pp ^= 1;
    __syncthreads();
  }
  for (int e = threadIdx.x; e < HH * 8; e += 256) {
    int row = e >> 3, cx = e & 7;
    int kx = x0 + cx;
    if (kx <= 128) {
      float tv = T[row * SW + kx];
      az[0][row][cx].x *= tv;
      az[0][row][cx].y *= tv;
    }
  }
  __syncthreads();
  pp = 0;
#pragma unroll
  for (int s = 0; s < 8; ++s) {
    int m = 1 << s;
#pragma unroll
    for (int q = 0; q < 4; ++q) {
      int tt = tb + q * 32;
      int jm = tt & ~(m - 1);
      float2 w = tw[jm];
      float2 a = az[pp][tt][col], b2 = az[pp][tt + 128][col];
      float dx = a.x - b2.x, dy = a.y - b2.y;
      az[pp ^ 1][tt + jm][col] = make_float2(a.x + b2.x, a.y + b2.y);
      az[pp ^ 1][tt + jm + m][col] = make_float2(w.x * dx + w.y * dy, w.x * dy - w.y * dx);
    }
    pp ^= 1;
    __syncthreads();
  }
  for (int e = threadIdx.x; e < HH * 8; e += 256) {
    int row = e >> 3, cx = e & 7;
    int kx = x0 + cx;
    if (kx <= 128) f[row * SW + kx] = az[0][row][cx];
  }
}

extern "C" void kernel_launch(void* const* d_in, const int* in_sizes, int n_in,
                              void* d_out, int out_size, void* d_ws, size_t ws_size,
                              hipStream_t stream) {
  const float* x = (const float*)d_in[0];
  const float* kerK = (const float*)d_in[1];
  const float* beta = (const float*)d_in[2];
  const float* rho = (const float*)d_in[3];
  float* out = (float*)d_out;
  float* ws = (float*)d_ws;

  const size_t PMU = (size_t)BATCH * CKCH * HH * WW;   // 6291456 floats
  const size_t SPL = (size_t)BATCH * CH * HSP;         // 1622016 float2
  float* muA = ws;
  float* muB = muA + PMU;
  float2* specA = (float2*)(muB + PMU);
  float2* specB = specA + SPL;
  float* Hinv = (float*)(specB + SPL);

  hinv2_kernel<<<30 * 128, 256, 0, stream>>>(kerK, rho, Hinv);

  for (int i = 0; i < NSTEPS; ++i) {
    float2* sIn = (i & 1) ? specA : specB;           // = sOut(i-1); unused for i==0
    float2* sOut = (i & 1) ? specB : specA;
    const float* mi = (i & 1) ? muB : muA;           // = muOut(i-1); unused i<=1
    float* mo = (i & 1) ? muA : muB;
    bigstep_kernel<<<BATCH * CH * 32, 256, 0, stream>>>(
        x, kerK, beta, rho, sIn, mi, mo, sOut, out, i);
    colfft_kernel<<<BATCH * CH * 17, 256, 0, stream>>>(sOut, Hinv, i);
  }
  // final: inverse row FFT of last spectra (in specB, since step 9 is odd) -> out
  bigstep_kernel<<<BATCH * CH * 32, 256, 0, stream>>>(
      x, kerK, beta, rho, specB, muA, muB, specA, out, 10);
}

// Round 4
// 430.461 us; speedup vs baseline: 2.6922x; 1.2644x over previous
//
#include <hip/hip_runtime.h>
#include <math.h>

#define BATCH 16
#define CH 3
#define CKCH 6
#define HH 256
#define WW 256
#define NSTEPS 10
#define SW 132                  // half-spectrum row stride (float2 units), 129 used
#define HSP (HH*SW)
#define IDX(i) ((i) ^ (((i) >> 4) & 15))

__device__ __forceinline__ float2 cmulf(float2 a, float2 b) {
  return make_float2(a.x * b.x - a.y * b.y, a.x * b.y + a.y * b.x);
}

// fused radix-2^2 Stockham FFT-256, one wave, data in buf[0..STRIDE) (swizzled via IDX),
// ping-pong second buffer at buf+STRIDE. Result lands back in buf[0..).
template <int INV, int STRIDE>
__device__ __forceinline__ void wave_fft256(float2* buf, const float2* tw, int l) {
  int pp = 0;
#pragma unroll
  for (int st = 0; st < 4; ++st) {
    int m = 1 << (2 * st);
    int r = l & (m - 1);
    int qm = l - r;
    float2 w1 = tw[qm], w2 = tw[qm + 64], w3 = tw[2 * qm];
    if (INV) { w1.y = -w1.y; w2.y = -w2.y; w3.y = -w3.y; }
    const float2* src = buf + pp * STRIDE;
    float2* dst = buf + (pp ^ 1) * STRIDE;
    float2 x0 = src[IDX(l)];
    float2 x1 = src[IDX(l + 128)];
    float2 x2 = src[IDX(l + 64)];
    float2 x3 = src[IDX(l + 192)];
    __builtin_amdgcn_wave_barrier();
    float2 aA = make_float2(x0.x + x1.x, x0.y + x1.y);
    float2 bA = cmulf(w1, make_float2(x0.x - x1.x, x0.y - x1.y));
    float2 aB = make_float2(x2.x + x3.x, x2.y + x3.y);
    float2 bB = cmulf(w2, make_float2(x2.x - x3.x, x2.y - x3.y));
    int base = 4 * qm + r;
    dst[IDX(base)]         = make_float2(aA.x + aB.x, aA.y + aB.y);
    dst[IDX(base + 2 * m)] = cmulf(w3, make_float2(aA.x - aB.x, aA.y - aB.y));
    dst[IDX(base + m)]     = make_float2(bA.x + bB.x, bA.y + bB.y);
    dst[IDX(base + 3 * m)] = cmulf(w3, make_float2(bA.x - bB.x, bA.y - bB.y));
    pp ^= 1;
    __builtin_amdgcn_wave_barrier();
  }
}

// ---------------- HinvT[i][c][kx][ky] = 1/(65536*OTF), coalesced ----------------
__global__ __launch_bounds__(256) void hinv3_kernel(const float* __restrict__ kerK,
                                                    const float* __restrict__ rho,
                                                    float* __restrict__ HinvT) {
  int bid = blockIdx.x;
  int kx = bid % 129;
  int ic = bid / 129;           // 0..29
  int c = ic % CH, i = ic / CH;
  __shared__ float kerH[25];
  __shared__ float ctab[256];
  int tid = threadIdx.x;
  if (tid < 25) {
    int a = tid / 5, b = tid % 5;
    float s = (a == 2 && b == 2) ? 1.0f : 0.0f;
    for (int o = 0; o < 2; ++o) {
      int ck = c * 2 + o;
      const float* Kk = kerK + (i * CKCH + ck) * 9;
      float rh = rho[i * CKCH + ck];
      float ac = 0.f;
      for (int ty = 0; ty < 3; ++ty)
        for (int tx = 0; tx < 3; ++tx) {
          int ya = a - 2 + ty, xb = b - 2 + tx;
          if (ya >= 0 && ya < 3 && xb >= 0 && xb < 3)
            ac += Kk[ya * 3 + xb] * Kk[ty * 3 + tx];
        }
      s += rh * ac;
    }
    kerH[tid] = s;
  }
  ctab[tid] = cosf(6.283185307179586f * (float)tid / 256.0f);
  __syncthreads();
  int ky = tid;
  float acc = 0.f;
#pragma unroll
  for (int a = 0; a < 5; ++a)
#pragma unroll
    for (int b = 0; b < 5; ++b)
      acc += kerH[a * 5 + b] * ctab[(ky * (a - 2) + kx * (b - 2)) & 255];
  HinvT[((size_t)ic * 129 + kx) * 256 + ky] = 1.0f / (65536.0f * acc);
}

// ------- bigstep: inv-rowFFT(prev spectra) + pmu(step-1) + w1(step) + fwd rowFFT -------
// wstep==0: w1=x only. wstep in 1..9: full. wstep==10: final inverse -> uout.
__global__ __launch_bounds__(256, 3) void bigstep_kernel(
    const float* __restrict__ xin, const float* __restrict__ kerK,
    const float* __restrict__ beta, const float* __restrict__ rho,
    const float2* __restrict__ specIn, const float* __restrict__ muIn,
    float* __restrict__ muOut, float2* __restrict__ specOut,
    float* __restrict__ uout, int wstep) {
  int bid = blockIdx.x;
  int strip = bid & 31;
  int bc = bid >> 5;
  int c = bc % CH, b = bc / CH;
  int y0 = strip * 8;
  int tid = threadIdx.x;
  int u = tid >> 6, l = tid & 63;
  bool final_ = (wstep == 10);
  bool first = (wstep == 0);

  __shared__ float su[12][264];          // u rows y0-2..y0+9, data at [4..259]
  __shared__ float sd[2][10][264];       // d = p-mu rows y0-1..y0+8
  __shared__ float2 zz[4][2][256];       // per-wave FFT ping-pong (swizzled)
  __shared__ float2 tw[128];

  if (tid < 128) {
    float sn, cs;
    sincosf(-6.283185307179586f * (float)tid / 256.0f, &sn, &cs);
    tw[tid] = make_float2(cs, sn);
  }
  __syncthreads();

  float2* Z = &zz[u][0][0];

  // ---- phase 1: packed inverse row FFTs (wave-local) ----
  if (wstep >= 1) {
    int nround = final_ ? 1 : 2;
    for (int round = 0; round < nround; ++round) {
      int j = final_ ? (u + 1) : (round * 4 + u);
      bool act = (j < 6);
      int ya = y0 - 2 + 2 * j;
      if (act && ya >= 0 && ya < HH) {
        const float2* Ar = specIn + ((size_t)bc * HH + ya) * SW;
        const float2* Br = Ar + SW;
#pragma unroll
        for (int h = 0; h < 2; ++h) {
          int t = l + h * 64;
          float2 A = Ar[t], B = Br[t];
          Z[IDX(t)] = make_float2(A.x - B.y, A.y + B.x);
          int mI = 128 - t;
          float2 Am = Ar[mI], Bm = Br[mI];
          float2 zh;
          if (t == 0) zh = make_float2(Am.x - Bm.y, Am.y + Bm.x);
          else        zh = make_float2(Am.x + Bm.y, Bm.x - Am.y);
          Z[IDX(t + 128)] = zh;
        }
        __builtin_amdgcn_wave_barrier();
        wave_fft256<1, 256>(Z, tw, l);
        if (final_) {
          float* oa = uout + ((size_t)bc * HH + ya) * WW;
#pragma unroll
          for (int h = 0; h < 4; ++h) {
            int xx = l + h * 64;
            float2 z = Z[IDX(xx)];
            oa[xx] = z.x;
            oa[WW + xx] = z.y;
          }
        } else {
          int r0 = 2 * j;
#pragma unroll
          for (int h = 0; h < 4; ++h) {
            int xx = l + h * 64;
            float2 z = Z[IDX(xx)];
            su[r0][4 + xx] = z.x;
            su[r0 + 1][4 + xx] = z.y;
          }
        }
      } else if (act) {
        int r0 = 2 * j;
        for (int k2 = l; k2 < 264; k2 += 64) { su[r0][k2] = 0.f; su[r0 + 1][k2] = 0.f; }
      }
    }
  }
  if (final_) return;

  // ---- phase 2: c = dwconv(K[step-1], u); soft-threshold; mu update; d -> sd ----
  if (!first) {
    __syncthreads();
    bool muZero = (wstep == 1);
    int ps = wstep - 1;
#pragma unroll 1
    for (int it = 0; it < 5; ++it) {
      int task = it * 4 + u;          // 0..19 = 2 o * 10 rows
      int o = task / 10, rr = task % 10;
      int y = y0 - 1 + rr;
      int ck = c * 2 + o;
      float4 dq = make_float4(0.f, 0.f, 0.f, 0.f);
      if (y >= 0 && y < HH) {
        const float* Kp = kerK + (ps * CKCH + ck) * 9;
        float kk[9];
#pragma unroll
        for (int q = 0; q < 9; ++q) kk[q] = Kp[q];
        float gm = beta[ps * CKCH + ck] / rho[ps * CKCH + ck];
        float4 c4 = make_float4(0.f, 0.f, 0.f, 0.f);
#pragma unroll
        for (int dy = 0; dy < 3; ++dy) {
          float4 mid = *(const float4*)&su[rr + dy][4 + 4 * l];
          float lft = __shfl_up(mid.w, 1); if (l == 0) lft = 0.f;
          float rgt = __shfl_down(mid.x, 1); if (l == 63) rgt = 0.f;
          float w0 = kk[dy * 3], w1 = kk[dy * 3 + 1], w2 = kk[dy * 3 + 2];
          c4.x += w0 * lft   + w1 * mid.x + w2 * mid.y;
          c4.y += w0 * mid.x + w1 * mid.y + w2 * mid.z;
          c4.z += w0 * mid.y + w1 * mid.z + w2 * mid.w;
          c4.w += w0 * mid.z + w1 * mid.w + w2 * rgt;
        }
        size_t gidx = (((size_t)b * CKCH + ck) * HH + y) * WW + 4 * l;
        float4 m4 = make_float4(0.f, 0.f, 0.f, 0.f);
        if (!muZero) m4 = *(const float4*)(muIn + gidx);
        float4 mn4;
        {
          float v = c4.x + m4.x, av = fabsf(v) - gm;
          float pn = (av > 0.f) ? ((v > 0.f) ? av : -av) : 0.f;
          mn4.x = m4.x + c4.x - pn; dq.x = pn - mn4.x;
        }
        {
          float v = c4.y + m4.y, av = fabsf(v) - gm;
          float pn = (av > 0.f) ? ((v > 0.f) ? av : -av) : 0.f;
          mn4.y = m4.y + c4.y - pn; dq.y = pn - mn4.y;
        }
        {
          float v = c4.z + m4.z, av = fabsf(v) - gm;
          float pn = (av > 0.f) ? ((v > 0.f) ? av : -av) : 0.f;
          mn4.z = m4.z + c4.z - pn; dq.z = pn - mn4.z;
        }
        {
          float v = c4.w + m4.w, av = fabsf(v) - gm;
          float pn = (av > 0.f) ? ((v > 0.f) ? av : -av) : 0.f;
          mn4.w = m4.w + c4.w - pn; dq.w = pn - mn4.w;
        }
        if (rr >= 1 && rr <= 8) *(float4*)(muOut + gidx) = mn4;
      }
      *(float4*)&sd[o][rr][4 + 4 * l] = dq;
    }
  }
  __syncthreads();

  // ---- phase 3: w1 = f + sum_o conv(rho*flipK, d); packed forward row FFT ----
  int ya = y0 + 2 * u;
  const float4* xa = (const float4*)(xin + ((size_t)(b * CH + c) * HH + ya) * WW);
  float4 va = xa[l], vb = xa[64 + l];
  if (!first) {
#pragma unroll
    for (int o = 0; o < 2; ++o) {
      int ck = c * 2 + o;
      float rh = rho[wstep * CKCH + ck];
      const float* Kk = kerK + (wstep * CKCH + ck) * 9;
      float kw[9];
#pragma unroll
      for (int dy = 0; dy < 3; ++dy)
#pragma unroll
        for (int dx = 0; dx < 3; ++dx)
          kw[dy * 3 + dx] = rh * Kk[(2 - dy) * 3 + (2 - dx)];
      float4 mid[4]; float lf[4], rg[4];
#pragma unroll
      for (int r4 = 0; r4 < 4; ++r4) {
        mid[r4] = *(const float4*)&sd[o][2 * u + r4][4 + 4 * l];
        lf[r4] = __shfl_up(mid[r4].w, 1); if (l == 0) lf[r4] = 0.f;
        rg[r4] = __shfl_down(mid[r4].x, 1); if (l == 63) rg[r4] = 0.f;
      }
#pragma unroll
      for (int dy = 0; dy < 3; ++dy) {
        float w0 = kw[dy * 3], w1 = kw[dy * 3 + 1], w2 = kw[dy * 3 + 2];
        va.x += w0 * lf[dy]     + w1 * mid[dy].x   + w2 * mid[dy].y;
        va.y += w0 * mid[dy].x  + w1 * mid[dy].y   + w2 * mid[dy].z;
        va.z += w0 * mid[dy].y  + w1 * mid[dy].z   + w2 * mid[dy].w;
        va.w += w0 * mid[dy].z  + w1 * mid[dy].w   + w2 * rg[dy];
        vb.x += w0 * lf[dy+1]    + w1 * mid[dy+1].x + w2 * mid[dy+1].y;
        vb.y += w0 * mid[dy+1].x + w1 * mid[dy+1].y + w2 * mid[dy+1].z;
        vb.z += w0 * mid[dy+1].y + w1 * mid[dy+1].z + w2 * mid[dy+1].w;
        vb.w += w0 * mid[dy+1].z + w1 * mid[dy+1].w + w2 * rg[dy+1];
      }
    }
  }
  Z[IDX(4 * l + 0)] = make_float2(va.x, vb.x);
  Z[IDX(4 * l + 1)] = make_float2(va.y, vb.y);
  Z[IDX(4 * l + 2)] = make_float2(va.z, vb.z);
  Z[IDX(4 * l + 3)] = make_float2(va.w, vb.w);
  __builtin_amdgcn_wave_barrier();
  wave_fft256<0, 256>(Z, tw, l);
  float2* Sa = specOut + ((size_t)bc * HH + ya) * SW;
  float2* Sb = Sa + SW;
#pragma unroll
  for (int h = 0; h < 2; ++h) {
    int k = l + h * 64;
    int mI = (256 - k) & 255;
    float2 zk = Z[IDX(k)], zm = Z[IDX(mI)];
    Sa[k] = make_float2(0.5f * (zk.x + zm.x), 0.5f * (zk.y - zm.y));
    Sb[k] = make_float2(0.5f * (zk.y + zm.y), 0.5f * (zm.x - zk.x));
  }
  if (l == 0) {
    float2 z1 = Z[IDX(128)];
    Sa[128] = make_float2(z1.x, 0.f);
    Sb[128] = make_float2(z1.y, 0.f);
  }
}

// ------- column FFT -> *HinvT -> inverse column FFT; wave-local, 2 cols/wave -------
__global__ __launch_bounds__(256, 4) void colfft_kernel(float2* __restrict__ spec,
                                                        const float* __restrict__ HinvT, int step) {
  int bid = blockIdx.x;
  int g = bid % 17;
  int bc = bid / 17;
  int c = bc % CH;
  int x0 = g * 8;
  float2* f = spec + (size_t)bc * HSP;

  __shared__ float2 az[8][2][258];
  __shared__ float2 tw[128];
  int tid = threadIdx.x;
  if (tid < 128) {
    float sn, cs;
    sincosf(-6.283185307179586f * (float)tid / 256.0f, &sn, &cs);
    tw[tid] = make_float2(cs, sn);
  }
  for (int e = tid; e < 2048; e += 256) {
    int row = e >> 3, col = e & 7;
    int kx = x0 + col;
    if (kx <= 128) az[col][0][IDX(row)] = f[row * SW + kx];
  }
  __syncthreads();

  int u = tid >> 6, l = tid & 63;
#pragma unroll
  for (int cc = 0; cc < 2; ++cc) {
    int col = 2 * u + cc;
    int kx = x0 + col;
    if (kx <= 128) {
      float2* A = &az[col][0][0];
      wave_fft256<0, 258>(A, tw, l);
      const float* T = HinvT + ((size_t)(step * CH + c) * 129 + kx) * 256;
#pragma unroll
      for (int h = 0; h < 4; ++h) {
        int idx = l + 64 * h;
        float tv = T[idx];
        float2 z = A[IDX(idx)];
        A[IDX(idx)] = make_float2(z.x * tv, z.y * tv);
      }
      __builtin_amdgcn_wave_barrier();
      wave_fft256<1, 258>(A, tw, l);
    }
  }
  __syncthreads();
  for (int e = tid; e < 2048; e += 256) {
    int row = e >> 3, col = e & 7;
    int kx = x0 + col;
    if (kx <= 128) f[row * SW + kx] = az[col][0][IDX(row)];
  }
}

extern "C" void kernel_launch(void* const* d_in, const int* in_sizes, int n_in,
                              void* d_out, int out_size, void* d_ws, size_t ws_size,
                              hipStream_t stream) {
  const float* x = (const float*)d_in[0];
  const float* kerK = (const float*)d_in[1];
  const float* beta = (const float*)d_in[2];
  const float* rho = (const float*)d_in[3];
  float* out = (float*)d_out;
  float* ws = (float*)d_ws;

  const size_t PMU = (size_t)BATCH * CKCH * HH * WW;   // 6291456 floats
  const size_t SPL = (size_t)BATCH * CH * HSP;         // 1622016 float2
  float* muA = ws;
  float* muB = muA + PMU;
  float2* specA = (float2*)(muB + PMU);
  float2* specB = specA + SPL;
  float* HinvT = (float*)(specB + SPL);

  hinv3_kernel<<<30 * 129, 256, 0, stream>>>(kerK, rho, HinvT);

  for (int i = 0; i < NSTEPS; ++i) {
    float2* sIn = (i & 1) ? specA : specB;           // = sOut(i-1); unused for i==0
    float2* sOut = (i & 1) ? specB : specA;
    const float* mi = (i & 1) ? muB : muA;           // = muOut(i-1); unused i<=1
    float* mo = (i & 1) ? muA : muB;
    bigstep_kernel<<<BATCH * CH * 32, 256, 0, stream>>>(
        x, kerK, beta, rho, sIn, mi, mo, sOut, out, i);
    colfft_kernel<<<BATCH * CH * 17, 256, 0, stream>>>(sOut, HinvT, i);
  }
  // final: inverse row FFT of last spectra (in specB, since step 9 is odd) -> out
  bigstep_kernel<<<BATCH * CH * 32, 256, 0, stream>>>(
      x, kerK, beta, rho, specB, muA, muB, specA, out, 10);
}

// Round 5
// 429.543 us; speedup vs baseline: 2.6980x; 1.0021x over previous
//
#include <hip/hip_runtime.h>
#include <hip/hip_fp16.h>
#include <math.h>

#define BATCH 16
#define CH 3
#define CKCH 6
#define HH 256
#define WW 256
#define NSTEPS 10
#define SW 132                  // half-spectrum row stride (__half2 units), 129 used
#define HSP (HH*SW)
#define IDX(i) ((i) ^ (((i) >> 4) & 15))

struct __align__(8) h4 { __half2 a, b; };

__device__ __forceinline__ float2 cmulf(float2 a, float2 b) {
  return make_float2(a.x * b.x - a.y * b.y, a.x * b.y + a.y * b.x);
}
__device__ __forceinline__ float4 h4tof4(h4 v) {
  float2 f0 = __half22float2(v.a), f1 = __half22float2(v.b);
  return make_float4(f0.x, f0.y, f1.x, f1.y);
}
__device__ __forceinline__ h4 f4toh4(float4 v) {
  h4 r;
  r.a = __float22half2_rn(make_float2(v.x, v.y));
  r.b = __float22half2_rn(make_float2(v.z, v.w));
  return r;
}

// fused radix-2^2 Stockham FFT-256, one wave, data in buf[0..STRIDE) (swizzled via IDX),
// ping-pong second buffer at buf+STRIDE. Result lands back in buf[0..).
template <int INV, int STRIDE>
__device__ __forceinline__ void wave_fft256(float2* buf, const float2* tw, int l) {
  int pp = 0;
#pragma unroll
  for (int st = 0; st < 4; ++st) {
    int m = 1 << (2 * st);
    int r = l & (m - 1);
    int qm = l - r;
    float2 w1 = tw[qm], w2 = tw[qm + 64], w3 = tw[2 * qm];
    if (INV) { w1.y = -w1.y; w2.y = -w2.y; w3.y = -w3.y; }
    const float2* src = buf + pp * STRIDE;
    float2* dst = buf + (pp ^ 1) * STRIDE;
    float2 x0 = src[IDX(l)];
    float2 x1 = src[IDX(l + 128)];
    float2 x2 = src[IDX(l + 64)];
    float2 x3 = src[IDX(l + 192)];
    __builtin_amdgcn_wave_barrier();
    float2 aA = make_float2(x0.x + x1.x, x0.y + x1.y);
    float2 bA = cmulf(w1, make_float2(x0.x - x1.x, x0.y - x1.y));
    float2 aB = make_float2(x2.x + x3.x, x2.y + x3.y);
    float2 bB = cmulf(w2, make_float2(x2.x - x3.x, x2.y - x3.y));
    int base = 4 * qm + r;
    dst[IDX(base)]         = make_float2(aA.x + aB.x, aA.y + aB.y);
    dst[IDX(base + 2 * m)] = cmulf(w3, make_float2(aA.x - aB.x, aA.y - aB.y));
    dst[IDX(base + m)]     = make_float2(bA.x + bB.x, bA.y + bB.y);
    dst[IDX(base + 3 * m)] = cmulf(w3, make_float2(bA.x - bB.x, bA.y - bB.y));
    pp ^= 1;
    __builtin_amdgcn_wave_barrier();
  }
}

// ---------------- x -> fp16 cast ----------------
__global__ __launch_bounds__(256) void xcast_kernel(const float4* __restrict__ x,
                                                    h4* __restrict__ xh) {
  int i = blockIdx.x * 256 + threadIdx.x;   // 786432 float4 groups
  xh[i] = f4toh4(x[i]);
}

// ---------------- HinvT[i][c][kx][ky] = 1/(65536*OTF), coalesced ----------------
__global__ __launch_bounds__(256) void hinv3_kernel(const float* __restrict__ kerK,
                                                    const float* __restrict__ rho,
                                                    float* __restrict__ HinvT) {
  int bid = blockIdx.x;
  int kx = bid % 129;
  int ic = bid / 129;           // 0..29
  int c = ic % CH, i = ic / CH;
  __shared__ float kerH[25];
  __shared__ float ctab[256];
  int tid = threadIdx.x;
  if (tid < 25) {
    int a = tid / 5, b = tid % 5;
    float s = (a == 2 && b == 2) ? 1.0f : 0.0f;
    for (int o = 0; o < 2; ++o) {
      int ck = c * 2 + o;
      const float* Kk = kerK + (i * CKCH + ck) * 9;
      float rh = rho[i * CKCH + ck];
      float ac = 0.f;
      for (int ty = 0; ty < 3; ++ty)
        for (int tx = 0; tx < 3; ++tx) {
          int ya = a - 2 + ty, xb = b - 2 + tx;
          if (ya >= 0 && ya < 3 && xb >= 0 && xb < 3)
            ac += Kk[ya * 3 + xb] * Kk[ty * 3 + tx];
        }
      s += rh * ac;
    }
    kerH[tid] = s;
  }
  ctab[tid] = cosf(6.283185307179586f * (float)tid / 256.0f);
  __syncthreads();
  int ky = tid;
  float acc = 0.f;
#pragma unroll
  for (int a = 0; a < 5; ++a)
#pragma unroll
    for (int b = 0; b < 5; ++b)
      acc += kerH[a * 5 + b] * ctab[(ky * (a - 2) + kx * (b - 2)) & 255];
  HinvT[((size_t)ic * 129 + kx) * 256 + ky] = 1.0f / (65536.0f * acc);
}

// ------- bigstep: inv-rowFFT(prev spectra) + pmu(step-1) + w1(step) + fwd rowFFT -------
// wstep==0: w1=x only. wstep in 1..9: full. wstep==10: final inverse -> uout (fp32).
__global__ __launch_bounds__(256, 3) void bigstep_kernel(
    const __half* __restrict__ xh, const float* __restrict__ kerK,
    const float* __restrict__ beta, const float* __restrict__ rho,
    const __half2* __restrict__ specIn, const __half* __restrict__ muIn,
    __half* __restrict__ muOut, __half2* __restrict__ specOut,
    float* __restrict__ uout, int wstep) {
  int bid = blockIdx.x;
  int strip = bid & 31;
  int bc = bid >> 5;
  int c = bc % CH, b = bc / CH;
  int y0 = strip * 8;
  int tid = threadIdx.x;
  int u = tid >> 6, l = tid & 63;
  bool final_ = (wstep == 10);
  bool first = (wstep == 0);

  __shared__ float su[12][264];          // u rows y0-2..y0+9, data at [4..259]
  __shared__ float sd[2][10][264];       // d = p-mu rows y0-1..y0+8
  __shared__ float2 zz[4][2][256];       // per-wave FFT ping-pong (swizzled)
  __shared__ float2 tw[128];

  if (tid < 128) {
    float sn, cs;
    sincosf(-6.283185307179586f * (float)tid / 256.0f, &sn, &cs);
    tw[tid] = make_float2(cs, sn);
  }
  __syncthreads();

  float2* Z = &zz[u][0][0];

  // ---- phase 1: packed inverse row FFTs (wave-local) ----
  if (wstep >= 1) {
    int nround = final_ ? 1 : 2;
    for (int round = 0; round < nround; ++round) {
      int j = final_ ? (u + 1) : (round * 4 + u);
      bool act = (j < 6);
      int ya = y0 - 2 + 2 * j;
      if (act && ya >= 0 && ya < HH) {
        const __half2* Ar = specIn + ((size_t)bc * HH + ya) * SW;
        const __half2* Br = Ar + SW;
#pragma unroll
        for (int h = 0; h < 2; ++h) {
          int t = l + h * 64;
          float2 A = __half22float2(Ar[t]), B = __half22float2(Br[t]);
          Z[IDX(t)] = make_float2(A.x - B.y, A.y + B.x);
          int mI = 128 - t;
          float2 Am = __half22float2(Ar[mI]), Bm = __half22float2(Br[mI]);
          float2 zh;
          if (t == 0) zh = make_float2(Am.x - Bm.y, Am.y + Bm.x);
          else        zh = make_float2(Am.x + Bm.y, Bm.x - Am.y);
          Z[IDX(t + 128)] = zh;
        }
        __builtin_amdgcn_wave_barrier();
        wave_fft256<1, 256>(Z, tw, l);
        if (final_) {
          float* oa = uout + ((size_t)bc * HH + ya) * WW;
#pragma unroll
          for (int h = 0; h < 4; ++h) {
            int xx = l + h * 64;
            float2 z = Z[IDX(xx)];
            oa[xx] = z.x;
            oa[WW + xx] = z.y;
          }
        } else {
          int r0 = 2 * j;
#pragma unroll
          for (int h = 0; h < 4; ++h) {
            int xx = l + h * 64;
            float2 z = Z[IDX(xx)];
            su[r0][4 + xx] = z.x;
            su[r0 + 1][4 + xx] = z.y;
          }
        }
      } else if (act) {
        int r0 = 2 * j;
        for (int k2 = l; k2 < 264; k2 += 64) { su[r0][k2] = 0.f; su[r0 + 1][k2] = 0.f; }
      }
    }
  }
  if (final_) return;

  // ---- phase 2: c = dwconv(K[step-1], u); soft-threshold; mu update; d -> sd ----
  if (!first) {
    __syncthreads();
    bool muZero = (wstep == 1);
    int ps = wstep - 1;
#pragma unroll 1
    for (int it = 0; it < 5; ++it) {
      int task = it * 4 + u;          // 0..19 = 2 o * 10 rows
      int o = task / 10, rr = task % 10;
      int y = y0 - 1 + rr;
      int ck = c * 2 + o;
      float4 dq = make_float4(0.f, 0.f, 0.f, 0.f);
      if (y >= 0 && y < HH) {
        const float* Kp = kerK + (ps * CKCH + ck) * 9;
        float kk[9];
#pragma unroll
        for (int q = 0; q < 9; ++q) kk[q] = Kp[q];
        float gm = beta[ps * CKCH + ck] / rho[ps * CKCH + ck];
        float4 c4 = make_float4(0.f, 0.f, 0.f, 0.f);
#pragma unroll
        for (int dy = 0; dy < 3; ++dy) {
          float4 mid = *(const float4*)&su[rr + dy][4 + 4 * l];
          float lft = __shfl_up(mid.w, 1); if (l == 0) lft = 0.f;
          float rgt = __shfl_down(mid.x, 1); if (l == 63) rgt = 0.f;
          float w0 = kk[dy * 3], w1 = kk[dy * 3 + 1], w2 = kk[dy * 3 + 2];
          c4.x += w0 * lft   + w1 * mid.x + w2 * mid.y;
          c4.y += w0 * mid.x + w1 * mid.y + w2 * mid.z;
          c4.z += w0 * mid.y + w1 * mid.z + w2 * mid.w;
          c4.w += w0 * mid.z + w1 * mid.w + w2 * rgt;
        }
        size_t gidx = (((size_t)b * CKCH + ck) * HH + y) * WW + 4 * l;
        float4 m4 = make_float4(0.f, 0.f, 0.f, 0.f);
        if (!muZero) m4 = h4tof4(*(const h4*)(muIn + gidx));
        float4 mn4;
        {
          float v = c4.x + m4.x, av = fabsf(v) - gm;
          float pn = (av > 0.f) ? ((v > 0.f) ? av : -av) : 0.f;
          mn4.x = m4.x + c4.x - pn; dq.x = pn - mn4.x;
        }
        {
          float v = c4.y + m4.y, av = fabsf(v) - gm;
          float pn = (av > 0.f) ? ((v > 0.f) ? av : -av) : 0.f;
          mn4.y = m4.y + c4.y - pn; dq.y = pn - mn4.y;
        }
        {
          float v = c4.z + m4.z, av = fabsf(v) - gm;
          float pn = (av > 0.f) ? ((v > 0.f) ? av : -av) : 0.f;
          mn4.z = m4.z + c4.z - pn; dq.z = pn - mn4.z;
        }
        {
          float v = c4.w + m4.w, av = fabsf(v) - gm;
          float pn = (av > 0.f) ? ((v > 0.f) ? av : -av) : 0.f;
          mn4.w = m4.w + c4.w - pn; dq.w = pn - mn4.w;
        }
        if (rr >= 1 && rr <= 8) *(h4*)(muOut + gidx) = f4toh4(mn4);
      }
      *(float4*)&sd[o][rr][4 + 4 * l] = dq;
    }
  }
  __syncthreads();

  // ---- phase 3: w1 = f + sum_o conv(rho*flipK, d); packed forward row FFT ----
  int ya = y0 + 2 * u;
  const h4* xa = (const h4*)(xh + ((size_t)(b * CH + c) * HH + ya) * WW);
  float4 va = h4tof4(xa[l]), vb = h4tof4(xa[64 + l]);
  if (!first) {
#pragma unroll
    for (int o = 0; o < 2; ++o) {
      int ck = c * 2 + o;
      float rh = rho[wstep * CKCH + ck];
      const float* Kk = kerK + (wstep * CKCH + ck) * 9;
      float kw[9];
#pragma unroll
      for (int dy = 0; dy < 3; ++dy)
#pragma unroll
        for (int dx = 0; dx < 3; ++dx)
          kw[dy * 3 + dx] = rh * Kk[(2 - dy) * 3 + (2 - dx)];
      float4 mid[4]; float lf[4], rg[4];
#pragma unroll
      for (int r4 = 0; r4 < 4; ++r4) {
        mid[r4] = *(const float4*)&sd[o][2 * u + r4][4 + 4 * l];
        lf[r4] = __shfl_up(mid[r4].w, 1); if (l == 0) lf[r4] = 0.f;
        rg[r4] = __shfl_down(mid[r4].x, 1); if (l == 63) rg[r4] = 0.f;
      }
#pragma unroll
      for (int dy = 0; dy < 3; ++dy) {
        float w0 = kw[dy * 3], w1 = kw[dy * 3 + 1], w2 = kw[dy * 3 + 2];
        va.x += w0 * lf[dy]     + w1 * mid[dy].x   + w2 * mid[dy].y;
        va.y += w0 * mid[dy].x  + w1 * mid[dy].y   + w2 * mid[dy].z;
        va.z += w0 * mid[dy].y  + w1 * mid[dy].z   + w2 * mid[dy].w;
        va.w += w0 * mid[dy].z  + w1 * mid[dy].w   + w2 * rg[dy];
        vb.x += w0 * lf[dy+1]    + w1 * mid[dy+1].x + w2 * mid[dy+1].y;
        vb.y += w0 * mid[dy+1].x + w1 * mid[dy+1].y + w2 * mid[dy+1].z;
        vb.z += w0 * mid[dy+1].y + w1 * mid[dy+1].z + w2 * mid[dy+1].w;
        vb.w += w0 * mid[dy+1].z + w1 * mid[dy+1].w + w2 * rg[dy+1];
      }
    }
  }
  Z[IDX(4 * l + 0)] = make_float2(va.x, vb.x);
  Z[IDX(4 * l + 1)] = make_float2(va.y, vb.y);
  Z[IDX(4 * l + 2)] = make_float2(va.z, vb.z);
  Z[IDX(4 * l + 3)] = make_float2(va.w, vb.w);
  __builtin_amdgcn_wave_barrier();
  wave_fft256<0, 256>(Z, tw, l);
  __half2* Sa = specOut + ((size_t)bc * HH + ya) * SW;
  __half2* Sb = Sa + SW;
#pragma unroll
  for (int h = 0; h < 2; ++h) {
    int k = l + h * 64;
    int mI = (256 - k) & 255;
    float2 zk = Z[IDX(k)], zm = Z[IDX(mI)];
    Sa[k] = __float22half2_rn(make_float2(0.5f * (zk.x + zm.x), 0.5f * (zk.y - zm.y)));
    Sb[k] = __float22half2_rn(make_float2(0.5f * (zk.y + zm.y), 0.5f * (zm.x - zk.x)));
  }
  if (l == 0) {
    float2 z1 = Z[IDX(128)];
    Sa[128] = __float22half2_rn(make_float2(z1.x, 0.f));
    Sb[128] = __float22half2_rn(make_float2(z1.y, 0.f));
  }
}

// ------- column FFT -> *HinvT -> inverse column FFT; wave-local, 2 cols/wave -------
__global__ __launch_bounds__(256, 4) void colfft_kernel(__half2* __restrict__ spec,
                                                        const float* __restrict__ HinvT, int step) {
  int bid = blockIdx.x;
  int g = bid % 17;
  int bc = bid / 17;
  int c = bc % CH;
  int x0 = g * 8;
  __half2* f = spec + (size_t)bc * HSP;

  __shared__ float2 az[8][2][258];
  __shared__ float2 tw[128];
  int tid = threadIdx.x;
  if (tid < 128) {
    float sn, cs;
    sincosf(-6.283185307179586f * (float)tid / 256.0f, &sn, &cs);
    tw[tid] = make_float2(cs, sn);
  }
  for (int e = tid; e < 2048; e += 256) {
    int row = e >> 3, col = e & 7;
    int kx = x0 + col;
    if (kx <= 128) az[col][0][IDX(row)] = __half22float2(f[row * SW + kx]);
  }
  __syncthreads();

  int u = tid >> 6, l = tid & 63;
#pragma unroll
  for (int cc = 0; cc < 2; ++cc) {
    int col = 2 * u + cc;
    int kx = x0 + col;
    if (kx <= 128) {
      float2* A = &az[col][0][0];
      wave_fft256<0, 258>(A, tw, l);
      const float* T = HinvT + ((size_t)(step * CH + c) * 129 + kx) * 256;
#pragma unroll
      for (int h = 0; h < 4; ++h) {
        int idx = l + 64 * h;
        float tv = T[idx];
        float2 z = A[IDX(idx)];
        A[IDX(idx)] = make_float2(z.x * tv, z.y * tv);
      }
      __builtin_amdgcn_wave_barrier();
      wave_fft256<1, 258>(A, tw, l);
    }
  }
  __syncthreads();
  for (int e = tid; e < 2048; e += 256) {
    int row = e >> 3, col = e & 7;
    int kx = x0 + col;
    if (kx <= 128) f[row * SW + kx] = __float22half2_rn(az[col][0][IDX(row)]);
  }
}

extern "C" void kernel_launch(void* const* d_in, const int* in_sizes, int n_in,
                              void* d_out, int out_size, void* d_ws, size_t ws_size,
                              hipStream_t stream) {
  const float* x = (const float*)d_in[0];
  const float* kerK = (const float*)d_in[1];
  const float* beta = (const float*)d_in[2];
  const float* rho = (const float*)d_in[3];
  float* out = (float*)d_out;

  const size_t PMU = (size_t)BATCH * CKCH * HH * WW;   // 6291456
  const size_t SPL = (size_t)BATCH * CH * HSP;         // 1622016 __half2
  const size_t XN = (size_t)BATCH * CH * HH * WW;      // 3145728

  __half* muA = (__half*)d_ws;
  __half* muB = muA + PMU;
  __half2* specA = (__half2*)(muB + PMU);
  __half2* specB = specA + SPL;
  float* HinvT = (float*)(specB + SPL);
  __half* xh = (__half*)(HinvT + (size_t)30 * 129 * 256);

  xcast_kernel<<<XN / 1024, 256, 0, stream>>>((const float4*)x, (h4*)xh);
  hinv3_kernel<<<30 * 129, 256, 0, stream>>>(kerK, rho, HinvT);

  for (int i = 0; i < NSTEPS; ++i) {
    __half2* sIn = (i & 1) ? specA : specB;          // = sOut(i-1); unused for i==0
    __half2* sOut = (i & 1) ? specB : specA;
    const __half* mi = (i & 1) ? muB : muA;          // = muOut(i-1); unused i<=1
    __half* mo = (i & 1) ? muA : muB;
    bigstep_kernel<<<BATCH * CH * 32, 256, 0, stream>>>(
        xh, kerK, beta, rho, sIn, mi, mo, sOut, out, i);
    colfft_kernel<<<BATCH * CH * 17, 256, 0, stream>>>(sOut, HinvT, i);
  }
  // final: inverse row FFT of last spectra (in specB, since step 9 is odd) -> out
  bigstep_kernel<<<BATCH * CH * 32, 256, 0, stream>>>(
      xh, kerK, beta, rho, specB, muA, muB, specA, out, 10);
}

// Round 6
// 414.990 us; speedup vs baseline: 2.7926x; 1.0351x over previous
//
#include <hip/hip_runtime.h>
#include <hip/hip_fp16.h>
#include <math.h>

#define BATCH 16
#define CH 3
#define CKCH 6
#define HH 256
#define WW 256
#define NSTEPS 10
#define SW 132                  // half-spectrum row stride (__half2 units), 129 used
#define HSP (HH*SW)
#define IDX(i) ((i) ^ (((i) >> 4) & 15))

struct __align__(8) h4 { __half2 a, b; };

__device__ __forceinline__ float2 cmulf(float2 a, float2 b) {
  return make_float2(a.x * b.x - a.y * b.y, a.x * b.y + a.y * b.x);
}
__device__ __forceinline__ float4 h4tof4(h4 v) {
  float2 f0 = __half22float2(v.a), f1 = __half22float2(v.b);
  return make_float4(f0.x, f0.y, f1.x, f1.y);
}
__device__ __forceinline__ h4 f4toh4(float4 v) {
  h4 r;
  r.a = __float22half2_rn(make_float2(v.x, v.y));
  r.b = __float22half2_rn(make_float2(v.z, v.w));
  return r;
}

// fused radix-2^2 Stockham FFT-256, one wave, IN-PLACE in buf[0..256) (swizzled via IDX).
// Safe in-place: all 4 reads issue before any write within the wave (per-wave in-order DS).
template <int INV>
__device__ __forceinline__ void wave_fft256(float2* buf, const float2* tw, int l) {
#pragma unroll
  for (int st = 0; st < 4; ++st) {
    int m = 1 << (2 * st);
    int r = l & (m - 1);
    int qm = l - r;
    float2 w1 = tw[qm], w2 = tw[qm + 64], w3 = tw[2 * qm];
    if (INV) { w1.y = -w1.y; w2.y = -w2.y; w3.y = -w3.y; }
    float2 x0 = buf[IDX(l)];
    float2 x1 = buf[IDX(l + 128)];
    float2 x2 = buf[IDX(l + 64)];
    float2 x3 = buf[IDX(l + 192)];
    __builtin_amdgcn_wave_barrier();
    float2 aA = make_float2(x0.x + x1.x, x0.y + x1.y);
    float2 bA = cmulf(w1, make_float2(x0.x - x1.x, x0.y - x1.y));
    float2 aB = make_float2(x2.x + x3.x, x2.y + x3.y);
    float2 bB = cmulf(w2, make_float2(x2.x - x3.x, x2.y - x3.y));
    int base = 4 * qm + r;
    buf[IDX(base)]         = make_float2(aA.x + aB.x, aA.y + aB.y);
    buf[IDX(base + 2 * m)] = cmulf(w3, make_float2(aA.x - aB.x, aA.y - aB.y));
    buf[IDX(base + m)]     = make_float2(bA.x + bB.x, bA.y + bB.y);
    buf[IDX(base + 3 * m)] = cmulf(w3, make_float2(bA.x - bB.x, bA.y - bB.y));
    __builtin_amdgcn_wave_barrier();
  }
}

// ---------------- x -> fp16 cast ----------------
__global__ __launch_bounds__(256) void xcast_kernel(const float4* __restrict__ x,
                                                    h4* __restrict__ xh) {
  int i = blockIdx.x * 256 + threadIdx.x;   // 786432 float4 groups
  xh[i] = f4toh4(x[i]);
}

// ---------------- HinvT[i][c][kx][ky] = 1/(65536*OTF), coalesced ----------------
__global__ __launch_bounds__(256) void hinv3_kernel(const float* __restrict__ kerK,
                                                    const float* __restrict__ rho,
                                                    float* __restrict__ HinvT) {
  int bid = blockIdx.x;
  int kx = bid % 129;
  int ic = bid / 129;           // 0..29
  int c = ic % CH, i = ic / CH;
  __shared__ float kerH[25];
  __shared__ float ctab[256];
  int tid = threadIdx.x;
  if (tid < 25) {
    int a = tid / 5, b = tid % 5;
    float s = (a == 2 && b == 2) ? 1.0f : 0.0f;
    for (int o = 0; o < 2; ++o) {
      int ck = c * 2 + o;
      const float* Kk = kerK + (i * CKCH + ck) * 9;
      float rh = rho[i * CKCH + ck];
      float ac = 0.f;
      for (int ty = 0; ty < 3; ++ty)
        for (int tx = 0; tx < 3; ++tx) {
          int ya = a - 2 + ty, xb = b - 2 + tx;
          if (ya >= 0 && ya < 3 && xb >= 0 && xb < 3)
            ac += Kk[ya * 3 + xb] * Kk[ty * 3 + tx];
        }
      s += rh * ac;
    }
    kerH[tid] = s;
  }
  ctab[tid] = cosf(6.283185307179586f * (float)tid / 256.0f);
  __syncthreads();
  int ky = tid;
  float acc = 0.f;
#pragma unroll
  for (int a = 0; a < 5; ++a)
#pragma unroll
    for (int b = 0; b < 5; ++b)
      acc += kerH[a * 5 + b] * ctab[(ky * (a - 2) + kx * (b - 2)) & 255];
  HinvT[((size_t)ic * 129 + kx) * 256 + ky] = 1.0f / (65536.0f * acc);
}

// ------- bigstep: inv-rowFFT(prev spectra) + pmu(step-1) + w1(step) + fwd rowFFT -------
// wstep==0: w1=x only. wstep in 1..9: full. wstep==10: final inverse -> uout (fp32).
// LDS budget 25.5KB -> 6 blocks/CU (24 waves/CU); grid 1536 = fully resident.
__global__ __launch_bounds__(256, 6) void bigstep_kernel(
    const __half* __restrict__ xh, const float* __restrict__ kerK,
    const float* __restrict__ beta, const float* __restrict__ rho,
    const __half2* __restrict__ specIn, const __half* __restrict__ muIn,
    __half* __restrict__ muOut, __half2* __restrict__ specOut,
    float* __restrict__ uout, int wstep) {
  int bid = blockIdx.x;
  int strip = bid & 31;
  int bc = bid >> 5;
  int c = bc % CH, b = bc / CH;
  int y0 = strip * 8;
  int tid = threadIdx.x;
  int u = tid >> 6, l = tid & 63;
  bool final_ = (wstep == 10);
  bool first = (wstep == 0);

  __shared__ __half su[12][264];         // u rows y0-2..y0+9, data at [4..259] (fp16)
  __shared__ __half sdm[2][10][264];     // d = p-mu rows y0-1..y0+8 (fp16)
  __shared__ float2 zz[4][256];          // per-wave in-place FFT buffer (swizzled)
  __shared__ float2 tw[128];

  if (tid < 128) {
    float sn, cs;
    sincosf(-6.283185307179586f * (float)tid / 256.0f, &sn, &cs);
    tw[tid] = make_float2(cs, sn);
  }
  __syncthreads();

  float2* Z = &zz[u][0];

  // ---- phase 1: packed inverse row FFTs (wave-local) ----
  if (wstep >= 1) {
    int nround = final_ ? 1 : 2;
    for (int round = 0; round < nround; ++round) {
      int j = final_ ? (u + 1) : (round * 4 + u);
      bool act = (j < 6);
      int ya = y0 - 2 + 2 * j;
      if (act && ya >= 0 && ya < HH) {
        const __half2* Ar = specIn + ((size_t)bc * HH + ya) * SW;
        const __half2* Br = Ar + SW;
#pragma unroll
        for (int h = 0; h < 2; ++h) {
          int t = l + h * 64;
          float2 A = __half22float2(Ar[t]), B = __half22float2(Br[t]);
          Z[IDX(t)] = make_float2(A.x - B.y, A.y + B.x);
          int mI = 128 - t;
          float2 Am = __half22float2(Ar[mI]), Bm = __half22float2(Br[mI]);
          float2 zh;
          if (t == 0) zh = make_float2(Am.x - Bm.y, Am.y + Bm.x);
          else        zh = make_float2(Am.x + Bm.y, Bm.x - Am.y);
          Z[IDX(t + 128)] = zh;
        }
        __builtin_amdgcn_wave_barrier();
        wave_fft256<1>(Z, tw, l);
        if (final_) {
          float* oa = uout + ((size_t)bc * HH + ya) * WW;
#pragma unroll
          for (int h = 0; h < 4; ++h) {
            int xx = l + h * 64;
            float2 z = Z[IDX(xx)];
            oa[xx] = z.x;
            oa[WW + xx] = z.y;
          }
        } else {
          int r0 = 2 * j;
#pragma unroll
          for (int h = 0; h < 4; ++h) {
            int xx = l + h * 64;
            float2 z = Z[IDX(xx)];
            su[r0][4 + xx] = __float2half(z.x);
            su[r0 + 1][4 + xx] = __float2half(z.y);
          }
        }
      } else if (act) {
        int r0 = 2 * j;
        for (int k2 = l; k2 < 264; k2 += 64) {
          su[r0][k2] = __float2half(0.f);
          su[r0 + 1][k2] = __float2half(0.f);
        }
      }
    }
  }
  if (final_) return;

  // ---- phase 2: c = dwconv(K[step-1], u); soft-threshold; mu update; d -> sdm ----
  if (!first) {
    __syncthreads();
    bool muZero = (wstep == 1);
    int ps = wstep - 1;
#pragma unroll 1
    for (int it = 0; it < 5; ++it) {
      int task = it * 4 + u;          // 0..19 = 2 o * 10 rows
      int o = task / 10, rr = task % 10;
      int y = y0 - 1 + rr;
      int ck = c * 2 + o;
      float4 dq = make_float4(0.f, 0.f, 0.f, 0.f);
      if (y >= 0 && y < HH) {
        const float* Kp = kerK + (ps * CKCH + ck) * 9;
        float kk[9];
#pragma unroll
        for (int q = 0; q < 9; ++q) kk[q] = Kp[q];
        float gm = beta[ps * CKCH + ck] / rho[ps * CKCH + ck];
        float4 c4 = make_float4(0.f, 0.f, 0.f, 0.f);
#pragma unroll
        for (int dy = 0; dy < 3; ++dy) {
          float4 mid = h4tof4(*(const h4*)&su[rr + dy][4 + 4 * l]);
          float lft = __shfl_up(mid.w, 1); if (l == 0) lft = 0.f;
          float rgt = __shfl_down(mid.x, 1); if (l == 63) rgt = 0.f;
          float w0 = kk[dy * 3], w1 = kk[dy * 3 + 1], w2 = kk[dy * 3 + 2];
          c4.x += w0 * lft   + w1 * mid.x + w2 * mid.y;
          c4.y += w0 * mid.x + w1 * mid.y + w2 * mid.z;
          c4.z += w0 * mid.y + w1 * mid.z + w2 * mid.w;
          c4.w += w0 * mid.z + w1 * mid.w + w2 * rgt;
        }
        size_t gidx = (((size_t)b * CKCH + ck) * HH + y) * WW + 4 * l;
        float4 m4 = make_float4(0.f, 0.f, 0.f, 0.f);
        if (!muZero) m4 = h4tof4(*(const h4*)(muIn + gidx));
        float4 mn4;
        {
          float v = c4.x + m4.x, av = fabsf(v) - gm;
          float pn = (av > 0.f) ? ((v > 0.f) ? av : -av) : 0.f;
          mn4.x = m4.x + c4.x - pn; dq.x = pn - mn4.x;
        }
        {
          float v = c4.y + m4.y, av = fabsf(v) - gm;
          float pn = (av > 0.f) ? ((v > 0.f) ? av : -av) : 0.f;
          mn4.y = m4.y + c4.y - pn; dq.y = pn - mn4.y;
        }
        {
          float v = c4.z + m4.z, av = fabsf(v) - gm;
          float pn = (av > 0.f) ? ((v > 0.f) ? av : -av) : 0.f;
          mn4.z = m4.z + c4.z - pn; dq.z = pn - mn4.z;
        }
        {
          float v = c4.w + m4.w, av = fabsf(v) - gm;
          float pn = (av > 0.f) ? ((v > 0.f) ? av : -av) : 0.f;
          mn4.w = m4.w + c4.w - pn; dq.w = pn - mn4.w;
        }
        if (rr >= 1 && rr <= 8) *(h4*)(muOut + gidx) = f4toh4(mn4);
      }
      *(h4*)&sdm[o][rr][4 + 4 * l] = f4toh4(dq);
    }
  }
  __syncthreads();

  // ---- phase 3: w1 = f + sum_o conv(rho*flipK, d); packed forward row FFT ----
  int ya = y0 + 2 * u;
  const h4* xa = (const h4*)(xh + ((size_t)(b * CH + c) * HH + ya) * WW);
  float4 va = h4tof4(xa[l]), vb = h4tof4(xa[64 + l]);
  if (!first) {
#pragma unroll
    for (int o = 0; o < 2; ++o) {
      int ck = c * 2 + o;
      float rh = rho[wstep * CKCH + ck];
      const float* Kk = kerK + (wstep * CKCH + ck) * 9;
      float kw[9];
#pragma unroll
      for (int dy = 0; dy < 3; ++dy)
#pragma unroll
        for (int dx = 0; dx < 3; ++dx)
          kw[dy * 3 + dx] = rh * Kk[(2 - dy) * 3 + (2 - dx)];
      float4 mid[4]; float lf[4], rg[4];
#pragma unroll
      for (int r4 = 0; r4 < 4; ++r4) {
        mid[r4] = h4tof4(*(const h4*)&sdm[o][2 * u + r4][4 + 4 * l]);
        lf[r4] = __shfl_up(mid[r4].w, 1); if (l == 0) lf[r4] = 0.f;
        rg[r4] = __shfl_down(mid[r4].x, 1); if (l == 63) rg[r4] = 0.f;
      }
#pragma unroll
      for (int dy = 0; dy < 3; ++dy) {
        float w0 = kw[dy * 3], w1 = kw[dy * 3 + 1], w2 = kw[dy * 3 + 2];
        va.x += w0 * lf[dy]     + w1 * mid[dy].x   + w2 * mid[dy].y;
        va.y += w0 * mid[dy].x  + w1 * mid[dy].y   + w2 * mid[dy].z;
        va.z += w0 * mid[dy].y  + w1 * mid[dy].z   + w2 * mid[dy].w;
        va.w += w0 * mid[dy].z  + w1 * mid[dy].w   + w2 * rg[dy];
        vb.x += w0 * lf[dy+1]    + w1 * mid[dy+1].x + w2 * mid[dy+1].y;
        vb.y += w0 * mid[dy+1].x + w1 * mid[dy+1].y + w2 * mid[dy+1].z;
        vb.z += w0 * mid[dy+1].y + w1 * mid[dy+1].z + w2 * mid[dy+1].w;
        vb.w += w0 * mid[dy+1].z + w1 * mid[dy+1].w + w2 * rg[dy+1];
      }
    }
  }
  Z[IDX(4 * l + 0)] = make_float2(va.x, vb.x);
  Z[IDX(4 * l + 1)] = make_float2(va.y, vb.y);
  Z[IDX(4 * l + 2)] = make_float2(va.z, vb.z);
  Z[IDX(4 * l + 3)] = make_float2(va.w, vb.w);
  __builtin_amdgcn_wave_barrier();
  wave_fft256<0>(Z, tw, l);
  __half2* Sa = specOut + ((size_t)bc * HH + ya) * SW;
  __half2* Sb = Sa + SW;
#pragma unroll
  for (int h = 0; h < 2; ++h) {
    int k = l + h * 64;
    int mI = (256 - k) & 255;
    float2 zk = Z[IDX(k)], zm = Z[IDX(mI)];
    Sa[k] = __float22half2_rn(make_float2(0.5f * (zk.x + zm.x), 0.5f * (zk.y - zm.y)));
    Sb[k] = __float22half2_rn(make_float2(0.5f * (zk.y + zm.y), 0.5f * (zm.x - zk.x)));
  }
  if (l == 0) {
    float2 z1 = Z[IDX(128)];
    Sa[128] = __float22half2_rn(make_float2(z1.x, 0.f));
    Sb[128] = __float22half2_rn(make_float2(z1.y, 0.f));
  }
}

// ------- column FFT -> *HinvT -> inverse column FFT; 1 col/wave, 8 waves/block -------
__global__ __launch_bounds__(512, 6) void colfft_kernel(__half2* __restrict__ spec,
                                                        const float* __restrict__ HinvT, int step) {
  int bid = blockIdx.x;
  int g = bid % 17;
  int bc = bid / 17;
  int c = bc % CH;
  int x0 = g * 8;
  __half2* f = spec + (size_t)bc * HSP;

  __shared__ float2 az[8][258];          // in-place per-wave FFT buffers (swizzled)
  __shared__ float2 tw[128];
  int tid = threadIdx.x;
  if (tid < 128) {
    float sn, cs;
    sincosf(-6.283185307179586f * (float)tid / 256.0f, &sn, &cs);
    tw[tid] = make_float2(cs, sn);
  }
  for (int e = tid; e < 2048; e += 512) {
    int row = e >> 3, col = e & 7;
    int kx = x0 + col;
    if (kx <= 128) az[col][IDX(row)] = __half22float2(f[row * SW + kx]);
  }
  __syncthreads();

  int u = tid >> 6, l = tid & 63;
  int kx = x0 + u;
  if (kx <= 128) {
    float2* A = &az[u][0];
    wave_fft256<0>(A, tw, l);
    const float* T = HinvT + ((size_t)(step * CH + c) * 129 + kx) * 256;
#pragma unroll
    for (int h = 0; h < 4; ++h) {
      int idx = l + 64 * h;
      float tv = T[idx];
      float2 z = A[IDX(idx)];
      A[IDX(idx)] = make_float2(z.x * tv, z.y * tv);
    }
    __builtin_amdgcn_wave_barrier();
    wave_fft256<1>(A, tw, l);
  }
  __syncthreads();
  for (int e = tid; e < 2048; e += 512) {
    int row = e >> 3, col = e & 7;
    int kx2 = x0 + col;
    if (kx2 <= 128) f[row * SW + kx2] = __float22half2_rn(az[col][IDX(row)]);
  }
}

extern "C" void kernel_launch(void* const* d_in, const int* in_sizes, int n_in,
                              void* d_out, int out_size, void* d_ws, size_t ws_size,
                              hipStream_t stream) {
  const float* x = (const float*)d_in[0];
  const float* kerK = (const float*)d_in[1];
  const float* beta = (const float*)d_in[2];
  const float* rho = (const float*)d_in[3];
  float* out = (float*)d_out;

  const size_t PMU = (size_t)BATCH * CKCH * HH * WW;   // 6291456
  const size_t SPL = (size_t)BATCH * CH * HSP;         // 1622016 __half2
  const size_t XN = (size_t)BATCH * CH * HH * WW;      // 3145728

  __half* muA = (__half*)d_ws;
  __half* muB = muA + PMU;
  __half2* specA = (__half2*)(muB + PMU);
  __half2* specB = specA + SPL;
  float* HinvT = (float*)(specB + SPL);
  __half* xh = (__half*)(HinvT + (size_t)30 * 129 * 256);

  xcast_kernel<<<XN / 1024, 256, 0, stream>>>((const float4*)x, (h4*)xh);
  hinv3_kernel<<<30 * 129, 256, 0, stream>>>(kerK, rho, HinvT);

  for (int i = 0; i < NSTEPS; ++i) {
    __half2* sIn = (i & 1) ? specA : specB;          // = sOut(i-1); unused for i==0
    __half2* sOut = (i & 1) ? specB : specA;
    const __half* mi = (i & 1) ? muB : muA;          // = muOut(i-1); unused i<=1
    __half* mo = (i & 1) ? muA : muB;
    bigstep_kernel<<<BATCH * CH * 32, 256, 0, stream>>>(
        xh, kerK, beta, rho, sIn, mi, mo, sOut, out, i);
    colfft_kernel<<<BATCH * CH * 17, 512, 0, stream>>>(sOut, HinvT, i);
  }
  // final: inverse row FFT of last spectra (in specB, since step 9 is odd) -> out
  bigstep_kernel<<<BATCH * CH * 32, 256, 0, stream>>>(
      xh, kerK, beta, rho, specB, muA, muB, specA, out, 10);
}